// Round 4
// baseline (346.484 us; speedup 1.0000x reference)
//
#include <hip/hip_runtime.h>
#include <math.h>

// ---------- GEMM v2: Y1 = X@W1, Y2 = X@W2 ; X [n,IN], W [IN,C] row-major ----------
// block = 2*C threads, 32 rows/block, k unrolled x4, xs broadcast from LDS.
template <int IN, int C>
__global__ __launch_bounds__(256) void gemm_two(
    const float* __restrict__ X, const float* __restrict__ W1,
    const float* __restrict__ W2, float* __restrict__ Y1,
    float* __restrict__ Y2, int n) {
    __shared__ float xs[32][IN];
    const int tid = threadIdx.x;
    const int nt = 2 * C;
    const int row0 = blockIdx.x * 32;
    {
        const int nv = 32 * (IN / 4);
        const float4* Xv = reinterpret_cast<const float4*>(X);
        float4* xsv = reinterpret_cast<float4*>(&xs[0][0]);
        for (int i = tid; i < nv; i += nt) {
            const int r = i / (IN / 4);
            const int gr = row0 + r;
            float4 v = {0.f, 0.f, 0.f, 0.f};
            if (gr < n) v = Xv[(size_t)gr * (IN / 4) + (i & (IN / 4 - 1))];
            xsv[i] = v;
        }
    }
    __syncthreads();
    const float* W = (tid < C) ? W1 : W2;
    float* Y = (tid < C) ? Y1 : Y2;
    const int col = (tid < C) ? tid : (tid - C);
    float acc[32];
#pragma unroll
    for (int r = 0; r < 32; ++r) acc[r] = 0.f;
    for (int k0 = 0; k0 < IN; k0 += 4) {
        const float w0 = W[(k0 + 0) * C + col];
        const float w1 = W[(k0 + 1) * C + col];
        const float w2 = W[(k0 + 2) * C + col];
        const float w3 = W[(k0 + 3) * C + col];
#pragma unroll
        for (int r = 0; r < 32; ++r) {
            const float4 xv = *reinterpret_cast<const float4*>(&xs[r][k0]);
            acc[r] = fmaf(xv.x, w0, acc[r]);
            acc[r] = fmaf(xv.y, w1, acc[r]);
            acc[r] = fmaf(xv.z, w2, acc[r]);
            acc[r] = fmaf(xv.w, w3, acc[r]);
        }
    }
#pragma unroll
    for (int r = 0; r < 32; ++r) {
        const int gr = row0 + r;
        if (gr < n) Y[(size_t)gr * C + col] = acc[r];
    }
}

// ---------- CSR build ----------
__global__ __launch_bounds__(256) void count_k(const int* __restrict__ dsts,
                                               int* __restrict__ cnt, int e0) {
    for (int i = blockIdx.x * blockDim.x + threadIdx.x; i < e0;
         i += gridDim.x * blockDim.x)
        atomicAdd(&cnt[dsts[i]], 1);
}

__global__ __launch_bounds__(256) void bsum_k(const int* __restrict__ cnt,
                                              int* __restrict__ bsum, int n) {
    __shared__ int red[256];
    const int t = threadIdx.x;
    const int i = blockIdx.x * 256 + t;
    red[t] = (i < n) ? cnt[i] + 1 : 0;
    __syncthreads();
#pragma unroll
    for (int s = 128; s > 0; s >>= 1) {
        if (t < s) red[t] += red[t + s];
        __syncthreads();
    }
    if (t == 0) bsum[blockIdx.x] = red[0];
}

// Requires nblocks <= 256 (n <= 65536).
__global__ __launch_bounds__(256) void scan2_k(const int* __restrict__ cnt,
                                               const int* __restrict__ bsum,
                                               int* __restrict__ row_ptr, int n) {
    __shared__ int red[256];
    const int b = blockIdx.x, t = threadIdx.x;
    red[t] = (t < b) ? bsum[t] : 0;
    __syncthreads();
#pragma unroll
    for (int s = 128; s > 0; s >>= 1) {
        if (t < s) red[t] += red[t + s];
        __syncthreads();
    }
    const int offset = red[0];
    __syncthreads();
    const int i = b * 256 + t;
    const int x = (i < n) ? cnt[i] + 1 : 0;
    red[t] = x;
    __syncthreads();
#pragma unroll
    for (int s = 1; s < 256; s <<= 1) {
        const int add = (t >= s) ? red[t - s] : 0;
        __syncthreads();
        red[t] += add;
        __syncthreads();
    }
    if (i < n) row_ptr[i] = offset + red[t] - x;
    if (i == n - 1) row_ptr[n] = offset + red[t];
}

__global__ __launch_bounds__(256) void fill_k(
    const int* __restrict__ srcs, const int* __restrict__ dsts,
    const int* __restrict__ row_ptr, int* __restrict__ cursor,
    int* __restrict__ csr_src, int e0, int etot) {
    for (int i = blockIdx.x * blockDim.x + threadIdx.x; i < etot;
         i += gridDim.x * blockDim.x) {
        int s, d;
        if (i < e0) { s = srcs[i]; d = dsts[i]; } else { s = d = i - e0; }
        int pos = atomicAdd(&cursor[d], 1);
        csr_src[row_ptr[d] + pos] = s;
    }
}

// ---------- fused per-dst softmax aggregation, H=2 ----------
// one wave per dst; 2 edge-groups x 32 lanes; each 32-lane group reads the
// full 128-float row (both heads); logits bounded -> no max subtraction.
__global__ __launch_bounds__(256) void gat_dst2_k(
    const float* __restrict__ xl, const float* __restrict__ xr,
    const int* __restrict__ row_ptr, const int* __restrict__ csr_src,
    const float* __restrict__ att, const float* __restrict__ bias,
    float* __restrict__ out, int n) {
    const int lane = threadIdx.x & 63;
    const int g = lane >> 5, l32 = lane & 31;
    const int d = (blockIdx.x * blockDim.x + threadIdx.x) >> 6;
    if (d >= n) return;

    const float4 xrv = reinterpret_cast<const float4*>(xr + (size_t)d * 128)[l32];
    const float4 atv = reinterpret_cast<const float4*>(att)[l32];
    const int rp0 = row_ptr[d], rp1 = row_ptr[d + 1];

    float s = 0.f;
    float4 acc = {0.f, 0.f, 0.f, 0.f};
    for (int i = rp0 + g; i < rp1; i += 2) {
        const int src = csr_src[i];
        const float4 a = reinterpret_cast<const float4*>(xl + (size_t)src * 128)[l32];
        float v, p = 0.f;
        v = a.x + xrv.x; p = fmaf(atv.x, (v > 0.f ? v : 0.2f * v), p);
        v = a.y + xrv.y; p = fmaf(atv.y, (v > 0.f ? v : 0.2f * v), p);
        v = a.z + xrv.z; p = fmaf(atv.z, (v > 0.f ? v : 0.2f * v), p);
        v = a.w + xrv.w; p = fmaf(atv.w, (v > 0.f ? v : 0.2f * v), p);
#pragma unroll
        for (int msk = 8; msk >= 1; msk >>= 1) p += __shfl_xor(p, msk, 64);
        const float wg = __expf(p);
        s += wg;
        acc.x = fmaf(wg, a.x, acc.x);
        acc.y = fmaf(wg, a.y, acc.y);
        acc.z = fmaf(wg, a.z, acc.z);
        acc.w = fmaf(wg, a.w, acc.w);
    }
    // combine the two edge-groups (lane <-> lane+32, same head position)
    s += __shfl_xor(s, 32, 64);
    acc.x += __shfl_xor(acc.x, 32, 64);
    acc.y += __shfl_xor(acc.y, 32, 64);
    acc.z += __shfl_xor(acc.z, 32, 64);
    acc.w += __shfl_xor(acc.w, 32, 64);
    if (g == 0) {
        const float inv = 1.f / (s + 1e-16f);
        const float4 bv = reinterpret_cast<const float4*>(bias)[l32];
        float4 o;
        o.x = fmaxf(fmaf(acc.x, inv, bv.x), 0.f);
        o.y = fmaxf(fmaf(acc.y, inv, bv.y), 0.f);
        o.z = fmaxf(fmaf(acc.z, inv, bv.z), 0.f);
        o.w = fmaxf(fmaf(acc.w, inv, bv.w), 0.f);
        reinterpret_cast<float4*>(out + (size_t)d * 128)[l32] = o;
    }
}

// ---------- fused per-dst softmax aggregation, H=1 (C=64) ----------
// one wave per dst; 4 edge-groups x 16 lanes.
__global__ __launch_bounds__(256) void gat_dst1_k(
    const float* __restrict__ xl, const float* __restrict__ xr,
    const int* __restrict__ row_ptr, const int* __restrict__ csr_src,
    const float* __restrict__ att, const float* __restrict__ bias,
    float* __restrict__ out, int n) {
    const int lane = threadIdx.x & 63;
    const int g = lane >> 4, l16 = lane & 15;
    const int d = (blockIdx.x * blockDim.x + threadIdx.x) >> 6;
    if (d >= n) return;

    const float4 xrv = reinterpret_cast<const float4*>(xr + (size_t)d * 64)[l16];
    const float4 atv = reinterpret_cast<const float4*>(att)[l16];
    const int rp0 = row_ptr[d], rp1 = row_ptr[d + 1];

    float s = 0.f;
    float4 acc = {0.f, 0.f, 0.f, 0.f};
    for (int i = rp0 + g; i < rp1; i += 4) {
        const int src = csr_src[i];
        const float4 a = reinterpret_cast<const float4*>(xl + (size_t)src * 64)[l16];
        float v, p = 0.f;
        v = a.x + xrv.x; p = fmaf(atv.x, (v > 0.f ? v : 0.2f * v), p);
        v = a.y + xrv.y; p = fmaf(atv.y, (v > 0.f ? v : 0.2f * v), p);
        v = a.z + xrv.z; p = fmaf(atv.z, (v > 0.f ? v : 0.2f * v), p);
        v = a.w + xrv.w; p = fmaf(atv.w, (v > 0.f ? v : 0.2f * v), p);
#pragma unroll
        for (int msk = 8; msk >= 1; msk >>= 1) p += __shfl_xor(p, msk, 64);
        const float wg = __expf(p);
        s += wg;
        acc.x = fmaf(wg, a.x, acc.x);
        acc.y = fmaf(wg, a.y, acc.y);
        acc.z = fmaf(wg, a.z, acc.z);
        acc.w = fmaf(wg, a.w, acc.w);
    }
#pragma unroll
    for (int off = 16; off <= 32; off <<= 1) {
        s += __shfl_xor(s, off, 64);
        acc.x += __shfl_xor(acc.x, off, 64);
        acc.y += __shfl_xor(acc.y, off, 64);
        acc.z += __shfl_xor(acc.z, off, 64);
        acc.w += __shfl_xor(acc.w, off, 64);
    }
    if (g == 0) {
        const float inv = 1.f / (s + 1e-16f);
        const float4 bv = reinterpret_cast<const float4*>(bias)[l16];
        float4 o;
        o.x = fmaxf(fmaf(acc.x, inv, bv.x), 0.f);
        o.y = fmaxf(fmaf(acc.y, inv, bv.y), 0.f);
        o.z = fmaxf(fmaf(acc.z, inv, bv.z), 0.f);
        o.w = fmaxf(fmaf(acc.w, inv, bv.w), 0.f);
        reinterpret_cast<float4*>(out + (size_t)d * 64)[l16] = o;
    }
}

extern "C" void kernel_launch(void* const* d_in, const int* in_sizes, int n_in,
                              void* d_out, int out_size, void* d_ws, size_t ws_size,
                              hipStream_t stream) {
    const float* x    = (const float*)d_in[0];
    const int*   ei   = (const int*)d_in[1];
    const float* Wl1  = (const float*)d_in[2];
    const float* Wr1  = (const float*)d_in[3];
    const float* att1 = (const float*)d_in[4];
    const float* b1   = (const float*)d_in[5];
    const float* Wl2  = (const float*)d_in[6];
    const float* Wr2  = (const float*)d_in[7];
    const float* att2 = (const float*)d_in[8];
    const float* b2   = (const float*)d_in[9];

    const int n    = in_sizes[0] / 128;   // 50000
    const int e0   = in_sizes[1] / 2;     // 800000
    const int etot = e0 + n;
    const int* srcs = ei;
    const int* dsts = ei + e0;

    float* ws = (float*)d_ws;
    float* xl = ws;                               // n*128
    float* xr = xl + (size_t)n * 128;             // n*128
    float* h1 = xr + (size_t)n * 128;             // n*128
    int* row_ptr = (int*)(h1 + (size_t)n * 128);  // n+1
    int* cnt     = row_ptr + (n + 1);             // n (reused as cursor)
    int* bsum    = cnt + n;                       // <=256
    int* csr_src = bsum + 256;                    // etot

    const int nb = (n + 255) / 256;  // 196 <= 256

    // ---- CSR build (graph identical for both layers) ----
    hipMemsetAsync(cnt, 0, (size_t)n * sizeof(int), stream);
    count_k<<<2048, 256, 0, stream>>>(dsts, cnt, e0);
    bsum_k<<<nb, 256, 0, stream>>>(cnt, bsum, n);
    scan2_k<<<nb, 256, 0, stream>>>(cnt, bsum, row_ptr, n);
    hipMemsetAsync(cnt, 0, (size_t)n * sizeof(int), stream);  // -> cursor
    fill_k<<<2048, 256, 0, stream>>>(srcs, dsts, row_ptr, cnt, csr_src, e0, etot);

    // ---- layer 1 (H=2, C=64) ----
    gemm_two<128, 128><<<(n + 31) / 32, 256, 0, stream>>>(x, Wl1, Wr1, xl, xr, n);
    gat_dst2_k<<<(n + 3) / 4, 256, 0, stream>>>(xl, xr, row_ptr, csr_src, att1, b1, h1, n);

    // ---- layer 2 (H=1, C=64) ----
    gemm_two<128, 64><<<(n + 31) / 32, 128, 0, stream>>>(h1, Wl2, Wr2, xl, xr, n);
    gat_dst1_k<<<(n + 3) / 4, 256, 0, stream>>>(xl, xr, row_ptr, csr_src, att2, b2,
                                                (float*)d_out, n);
}

// Round 5
// 281.111 us; speedup vs baseline: 1.2326x; 1.2326x over previous
//
#include <hip/hip_runtime.h>
#include <math.h>

// ---------- register-blocked GEMM: Y1 = X@W1, Y2 = X@W2 ----------
// X [n][IN], W [IN][C] row-major. BM=128, BN=64, BK=32, 256 threads, 8x4/thread.
// grid.y slabs: [0, C/64) -> W1/Y1, [C/64, 2C/64) -> W2/Y2.
template <int IN, int C>
__global__ __launch_bounds__(256) void gemm_rb(
    const float* __restrict__ X, const float* __restrict__ W1,
    const float* __restrict__ W2, float* __restrict__ Y1,
    float* __restrict__ Y2, int n) {
    constexpr int BM = 128, BN = 64, BK = 32;
    constexpr int NB1 = C / BN;
    __shared__ float Xs[BK][BM + 4];
    __shared__ float Ws[BK][BN + 4];
    const int t = threadIdx.x;
    const int row0 = blockIdx.x * BM;
    const int slab = blockIdx.y;
    const float* __restrict__ W = (slab < NB1) ? W1 : W2;
    float* __restrict__ Y = (slab < NB1) ? Y1 : Y2;
    const int colbase = (slab % NB1) * BN;

    const int tx = t & 15, ty = t >> 4;
    const int n0 = tx * 4, m0 = ty * 8;

    float acc[8][4];
#pragma unroll
    for (int r = 0; r < 8; ++r)
#pragma unroll
        for (int q = 0; q < 4; ++q) acc[r][q] = 0.f;

    for (int k0 = 0; k0 < IN; k0 += BK) {
        // X tile: 128x32 floats = 1024 float4, 4 per thread; transpose into Xs[k][m]
#pragma unroll
        for (int j = 0; j < 4; ++j) {
            const int c = t + 256 * j;
            const int m = c >> 3, kq = (c & 7) * 4;
            const int gr = row0 + m;
            float4 v = {0.f, 0.f, 0.f, 0.f};
            if (gr < n)
                v = *reinterpret_cast<const float4*>(&X[(size_t)gr * IN + k0 + kq]);
            Xs[kq + 0][m] = v.x;
            Xs[kq + 1][m] = v.y;
            Xs[kq + 2][m] = v.z;
            Xs[kq + 3][m] = v.w;
        }
        // W tile: 32xBN floats, direct float4 copy
#pragma unroll
        for (int j = 0; j < (BK * BN / 4) / 256; ++j) {
            const int c = t + 256 * j;
            const int k = c / (BN / 4), nq = (c % (BN / 4)) * 4;
            *reinterpret_cast<float4*>(&Ws[k][nq]) =
                *reinterpret_cast<const float4*>(&W[(size_t)(k0 + k) * C + colbase + nq]);
        }
        __syncthreads();
#pragma unroll 8
        for (int k = 0; k < BK; ++k) {
            const float4 b = *reinterpret_cast<const float4*>(&Ws[k][n0]);
            const float4 a0 = *reinterpret_cast<const float4*>(&Xs[k][m0]);
            const float4 a1 = *reinterpret_cast<const float4*>(&Xs[k][m0 + 4]);
            const float av[8] = {a0.x, a0.y, a0.z, a0.w, a1.x, a1.y, a1.z, a1.w};
            const float bv[4] = {b.x, b.y, b.z, b.w};
#pragma unroll
            for (int r = 0; r < 8; ++r)
#pragma unroll
                for (int q = 0; q < 4; ++q) acc[r][q] = fmaf(av[r], bv[q], acc[r][q]);
        }
        __syncthreads();
    }
#pragma unroll
    for (int r = 0; r < 8; ++r) {
        const int gr = row0 + m0 + r;
        if (gr < n) {
            const float4 o = {acc[r][0], acc[r][1], acc[r][2], acc[r][3]};
            *reinterpret_cast<float4*>(&Y[(size_t)gr * C + colbase + n0]) = o;
        }
    }
}

// ---------- CSR build ----------
__global__ __launch_bounds__(256) void count_k(const int* __restrict__ dsts,
                                               int* __restrict__ cnt, int e0) {
    for (int i = blockIdx.x * blockDim.x + threadIdx.x; i < e0;
         i += gridDim.x * blockDim.x)
        atomicAdd(&cnt[dsts[i]], 1);
}

__global__ __launch_bounds__(256) void bsum_k(const int* __restrict__ cnt,
                                              int* __restrict__ bsum, int n) {
    __shared__ int red[256];
    const int t = threadIdx.x;
    const int i = blockIdx.x * 256 + t;
    red[t] = (i < n) ? cnt[i] + 1 : 0;
    __syncthreads();
#pragma unroll
    for (int s = 128; s > 0; s >>= 1) {
        if (t < s) red[t] += red[t + s];
        __syncthreads();
    }
    if (t == 0) bsum[blockIdx.x] = red[0];
}

// Requires nblocks <= 256 (n <= 65536).
__global__ __launch_bounds__(256) void scan2_k(const int* __restrict__ cnt,
                                               const int* __restrict__ bsum,
                                               int* __restrict__ row_ptr, int n) {
    __shared__ int red[256];
    const int b = blockIdx.x, t = threadIdx.x;
    red[t] = (t < b) ? bsum[t] : 0;
    __syncthreads();
#pragma unroll
    for (int s = 128; s > 0; s >>= 1) {
        if (t < s) red[t] += red[t + s];
        __syncthreads();
    }
    const int offset = red[0];
    __syncthreads();
    const int i = b * 256 + t;
    const int x = (i < n) ? cnt[i] + 1 : 0;
    red[t] = x;
    __syncthreads();
#pragma unroll
    for (int s = 1; s < 256; s <<= 1) {
        const int add = (t >= s) ? red[t - s] : 0;
        __syncthreads();
        red[t] += add;
        __syncthreads();
    }
    if (i < n) row_ptr[i] = offset + red[t] - x;
    if (i == n - 1) row_ptr[n] = offset + red[t];
}

__global__ __launch_bounds__(256) void fill_k(
    const int* __restrict__ srcs, const int* __restrict__ dsts,
    const int* __restrict__ row_ptr, int* __restrict__ cursor,
    int* __restrict__ csr_src, int e0, int etot) {
    for (int i = blockIdx.x * blockDim.x + threadIdx.x; i < etot;
         i += gridDim.x * blockDim.x) {
        int s, d;
        if (i < e0) { s = srcs[i]; d = dsts[i]; } else { s = d = i - e0; }
        int pos = atomicAdd(&cursor[d], 1);
        csr_src[row_ptr[d] + pos] = s;
    }
}

// ---------- fused per-dst softmax aggregation, H=2 (HC=128) ----------
// one wave per dst; 2 edge-groups x 32 lanes; unroll-2 with dual loads.
__global__ __launch_bounds__(256) void gat_dst2_k(
    const float* __restrict__ xl, const float* __restrict__ xr,
    const int* __restrict__ row_ptr, const int* __restrict__ csr_src,
    const float* __restrict__ att, const float* __restrict__ bias,
    float* __restrict__ out, int n) {
    const int lane = threadIdx.x & 63;
    const int g = lane >> 5, l32 = lane & 31;
    const int d = (blockIdx.x * blockDim.x + threadIdx.x) >> 6;
    if (d >= n) return;

    const float4 xrv = reinterpret_cast<const float4*>(xr + (size_t)d * 128)[l32];
    const float4 atv = reinterpret_cast<const float4*>(att)[l32];
    const int rp0 = row_ptr[d], rp1 = row_ptr[d + 1];

    float s = 0.f;
    float4 acc = {0.f, 0.f, 0.f, 0.f};
    int i = rp0 + g;
    for (; i + 2 < rp1; i += 4) {
        const int s0 = csr_src[i];
        const int s1 = csr_src[i + 2];
        const float4 a0 = reinterpret_cast<const float4*>(xl + (size_t)s0 * 128)[l32];
        const float4 a1 = reinterpret_cast<const float4*>(xl + (size_t)s1 * 128)[l32];
        float v, p0 = 0.f, p1 = 0.f;
        v = a0.x + xrv.x; p0 = fmaf(atv.x, (v > 0.f ? v : 0.2f * v), p0);
        v = a0.y + xrv.y; p0 = fmaf(atv.y, (v > 0.f ? v : 0.2f * v), p0);
        v = a0.z + xrv.z; p0 = fmaf(atv.z, (v > 0.f ? v : 0.2f * v), p0);
        v = a0.w + xrv.w; p0 = fmaf(atv.w, (v > 0.f ? v : 0.2f * v), p0);
        v = a1.x + xrv.x; p1 = fmaf(atv.x, (v > 0.f ? v : 0.2f * v), p1);
        v = a1.y + xrv.y; p1 = fmaf(atv.y, (v > 0.f ? v : 0.2f * v), p1);
        v = a1.z + xrv.z; p1 = fmaf(atv.z, (v > 0.f ? v : 0.2f * v), p1);
        v = a1.w + xrv.w; p1 = fmaf(atv.w, (v > 0.f ? v : 0.2f * v), p1);
#pragma unroll
        for (int msk = 8; msk >= 1; msk >>= 1) {
            p0 += __shfl_xor(p0, msk, 64);
            p1 += __shfl_xor(p1, msk, 64);
        }
        const float w0 = __expf(p0), w1 = __expf(p1);
        s += w0 + w1;
        acc.x = fmaf(w0, a0.x, fmaf(w1, a1.x, acc.x));
        acc.y = fmaf(w0, a0.y, fmaf(w1, a1.y, acc.y));
        acc.z = fmaf(w0, a0.z, fmaf(w1, a1.z, acc.z));
        acc.w = fmaf(w0, a0.w, fmaf(w1, a1.w, acc.w));
    }
    if (i < rp1) {
        const int s0 = csr_src[i];
        const float4 a0 = reinterpret_cast<const float4*>(xl + (size_t)s0 * 128)[l32];
        float v, p0 = 0.f;
        v = a0.x + xrv.x; p0 = fmaf(atv.x, (v > 0.f ? v : 0.2f * v), p0);
        v = a0.y + xrv.y; p0 = fmaf(atv.y, (v > 0.f ? v : 0.2f * v), p0);
        v = a0.z + xrv.z; p0 = fmaf(atv.z, (v > 0.f ? v : 0.2f * v), p0);
        v = a0.w + xrv.w; p0 = fmaf(atv.w, (v > 0.f ? v : 0.2f * v), p0);
#pragma unroll
        for (int msk = 8; msk >= 1; msk >>= 1) p0 += __shfl_xor(p0, msk, 64);
        const float w0 = __expf(p0);
        s += w0;
        acc.x = fmaf(w0, a0.x, acc.x);
        acc.y = fmaf(w0, a0.y, acc.y);
        acc.z = fmaf(w0, a0.z, acc.z);
        acc.w = fmaf(w0, a0.w, acc.w);
    }
    s += __shfl_xor(s, 32, 64);
    acc.x += __shfl_xor(acc.x, 32, 64);
    acc.y += __shfl_xor(acc.y, 32, 64);
    acc.z += __shfl_xor(acc.z, 32, 64);
    acc.w += __shfl_xor(acc.w, 32, 64);
    if (g == 0) {
        const float inv = 1.f / (s + 1e-16f);
        const float4 bv = reinterpret_cast<const float4*>(bias)[l32];
        float4 o;
        o.x = fmaxf(fmaf(acc.x, inv, bv.x), 0.f);
        o.y = fmaxf(fmaf(acc.y, inv, bv.y), 0.f);
        o.z = fmaxf(fmaf(acc.z, inv, bv.z), 0.f);
        o.w = fmaxf(fmaf(acc.w, inv, bv.w), 0.f);
        reinterpret_cast<float4*>(out + (size_t)d * 128)[l32] = o;
    }
}

// ---------- fused per-dst softmax aggregation, H=1 (C=64) ----------
// one wave per dst; 4 edge-groups x 16 lanes; unroll-2 with dual loads.
__global__ __launch_bounds__(256) void gat_dst1_k(
    const float* __restrict__ xl, const float* __restrict__ xr,
    const int* __restrict__ row_ptr, const int* __restrict__ csr_src,
    const float* __restrict__ att, const float* __restrict__ bias,
    float* __restrict__ out, int n) {
    const int lane = threadIdx.x & 63;
    const int g = lane >> 4, l16 = lane & 15;
    const int d = (blockIdx.x * blockDim.x + threadIdx.x) >> 6;
    if (d >= n) return;

    const float4 xrv = reinterpret_cast<const float4*>(xr + (size_t)d * 64)[l16];
    const float4 atv = reinterpret_cast<const float4*>(att)[l16];
    const int rp0 = row_ptr[d], rp1 = row_ptr[d + 1];

    float s = 0.f;
    float4 acc = {0.f, 0.f, 0.f, 0.f};
    int i = rp0 + g;
    for (; i + 4 < rp1; i += 8) {
        const int s0 = csr_src[i];
        const int s1 = csr_src[i + 4];
        const float4 a0 = reinterpret_cast<const float4*>(xl + (size_t)s0 * 64)[l16];
        const float4 a1 = reinterpret_cast<const float4*>(xl + (size_t)s1 * 64)[l16];
        float v, p0 = 0.f, p1 = 0.f;
        v = a0.x + xrv.x; p0 = fmaf(atv.x, (v > 0.f ? v : 0.2f * v), p0);
        v = a0.y + xrv.y; p0 = fmaf(atv.y, (v > 0.f ? v : 0.2f * v), p0);
        v = a0.z + xrv.z; p0 = fmaf(atv.z, (v > 0.f ? v : 0.2f * v), p0);
        v = a0.w + xrv.w; p0 = fmaf(atv.w, (v > 0.f ? v : 0.2f * v), p0);
        v = a1.x + xrv.x; p1 = fmaf(atv.x, (v > 0.f ? v : 0.2f * v), p1);
        v = a1.y + xrv.y; p1 = fmaf(atv.y, (v > 0.f ? v : 0.2f * v), p1);
        v = a1.z + xrv.z; p1 = fmaf(atv.z, (v > 0.f ? v : 0.2f * v), p1);
        v = a1.w + xrv.w; p1 = fmaf(atv.w, (v > 0.f ? v : 0.2f * v), p1);
#pragma unroll
        for (int msk = 8; msk >= 1; msk >>= 1) {
            p0 += __shfl_xor(p0, msk, 64);
            p1 += __shfl_xor(p1, msk, 64);
        }
        const float w0 = __expf(p0), w1 = __expf(p1);
        s += w0 + w1;
        acc.x = fmaf(w0, a0.x, fmaf(w1, a1.x, acc.x));
        acc.y = fmaf(w0, a0.y, fmaf(w1, a1.y, acc.y));
        acc.z = fmaf(w0, a0.z, fmaf(w1, a1.z, acc.z));
        acc.w = fmaf(w0, a0.w, fmaf(w1, a1.w, acc.w));
    }
    if (i < rp1) {
        const int s0 = csr_src[i];
        const float4 a0 = reinterpret_cast<const float4*>(xl + (size_t)s0 * 64)[l16];
        float v, p0 = 0.f;
        v = a0.x + xrv.x; p0 = fmaf(atv.x, (v > 0.f ? v : 0.2f * v), p0);
        v = a0.y + xrv.y; p0 = fmaf(atv.y, (v > 0.f ? v : 0.2f * v), p0);
        v = a0.z + xrv.z; p0 = fmaf(atv.z, (v > 0.f ? v : 0.2f * v), p0);
        v = a0.w + xrv.w; p0 = fmaf(atv.w, (v > 0.f ? v : 0.2f * v), p0);
#pragma unroll
        for (int msk = 8; msk >= 1; msk >>= 1) p0 += __shfl_xor(p0, msk, 64);
        const float w0 = __expf(p0);
        s += w0;
        acc.x = fmaf(w0, a0.x, acc.x);
        acc.y = fmaf(w0, a0.y, acc.y);
        acc.z = fmaf(w0, a0.z, acc.z);
        acc.w = fmaf(w0, a0.w, acc.w);
    }
#pragma unroll
    for (int off = 16; off <= 32; off <<= 1) {
        s += __shfl_xor(s, off, 64);
        acc.x += __shfl_xor(acc.x, off, 64);
        acc.y += __shfl_xor(acc.y, off, 64);
        acc.z += __shfl_xor(acc.z, off, 64);
        acc.w += __shfl_xor(acc.w, off, 64);
    }
    if (g == 0) {
        const float inv = 1.f / (s + 1e-16f);
        const float4 bv = reinterpret_cast<const float4*>(bias)[l16];
        float4 o;
        o.x = fmaxf(fmaf(acc.x, inv, bv.x), 0.f);
        o.y = fmaxf(fmaf(acc.y, inv, bv.y), 0.f);
        o.z = fmaxf(fmaf(acc.z, inv, bv.z), 0.f);
        o.w = fmaxf(fmaf(acc.w, inv, bv.w), 0.f);
        reinterpret_cast<float4*>(out + (size_t)d * 64)[l16] = o;
    }
}

extern "C" void kernel_launch(void* const* d_in, const int* in_sizes, int n_in,
                              void* d_out, int out_size, void* d_ws, size_t ws_size,
                              hipStream_t stream) {
    const float* x    = (const float*)d_in[0];
    const int*   ei   = (const int*)d_in[1];
    const float* Wl1  = (const float*)d_in[2];
    const float* Wr1  = (const float*)d_in[3];
    const float* att1 = (const float*)d_in[4];
    const float* b1   = (const float*)d_in[5];
    const float* Wl2  = (const float*)d_in[6];
    const float* Wr2  = (const float*)d_in[7];
    const float* att2 = (const float*)d_in[8];
    const float* b2   = (const float*)d_in[9];

    const int n    = in_sizes[0] / 128;   // 50000
    const int e0   = in_sizes[1] / 2;     // 800000
    const int etot = e0 + n;
    const int* srcs = ei;
    const int* dsts = ei + e0;

    float* ws = (float*)d_ws;
    float* xl = ws;                               // n*128
    float* xr = xl + (size_t)n * 128;             // n*128
    float* h1 = xr + (size_t)n * 128;             // n*128
    int* row_ptr = (int*)(h1 + (size_t)n * 128);  // n+1
    int* cnt     = row_ptr + (n + 1);             // n (reused as cursor)
    int* bsum    = cnt + n;                       // <=256
    int* csr_src = bsum + 256;                    // etot

    const int nb = (n + 255) / 256;  // 196 <= 256

    // ---- CSR build (graph identical for both layers) ----
    hipMemsetAsync(cnt, 0, (size_t)n * sizeof(int), stream);
    count_k<<<2048, 256, 0, stream>>>(dsts, cnt, e0);
    bsum_k<<<nb, 256, 0, stream>>>(cnt, bsum, n);
    scan2_k<<<nb, 256, 0, stream>>>(cnt, bsum, row_ptr, n);
    hipMemsetAsync(cnt, 0, (size_t)n * sizeof(int), stream);  // -> cursor
    fill_k<<<2048, 256, 0, stream>>>(srcs, dsts, row_ptr, cnt, csr_src, e0, etot);

    const int mb = (n + 127) / 128;  // 391

    // ---- layer 1 (H=2, C=128 per W) ----
    gemm_rb<128, 128><<<dim3(mb, 4), 256, 0, stream>>>(x, Wl1, Wr1, xl, xr, n);
    gat_dst2_k<<<(n + 3) / 4, 256, 0, stream>>>(xl, xr, row_ptr, csr_src, att1, b1, h1, n);

    // ---- layer 2 (H=1, C=64 per W) ----
    gemm_rb<128, 64><<<dim3(mb, 2), 256, 0, stream>>>(h1, Wl2, Wr2, xl, xr, n);
    gat_dst1_k<<<(n + 3) / 4, 256, 0, stream>>>(xl, xr, row_ptr, csr_src, att2, b2,
                                                (float*)d_out, n);
}

// Round 6
// 270.266 us; speedup vs baseline: 1.2820x; 1.0401x over previous
//
#include <hip/hip_runtime.h>
#include <math.h>

// ---------- bf16 helpers ----------
__device__ __forceinline__ unsigned short f2bf(float f) {
    unsigned u = __float_as_uint(f);
    u += 0x7FFFu + ((u >> 16) & 1u);
    return (unsigned short)(u >> 16);
}
__device__ __forceinline__ float4 bf4_to_f4(ushort4 u) {
    float4 r;
    r.x = __uint_as_float((unsigned)u.x << 16);
    r.y = __uint_as_float((unsigned)u.y << 16);
    r.z = __uint_as_float((unsigned)u.z << 16);
    r.w = __uint_as_float((unsigned)u.w << 16);
    return r;
}

// ---------- register-blocked GEMM: Ybf = X@W1 (bf16), Yf = X@W2 (fp32) ----------
// X [n][IN], W [IN][C] row-major. BM=128, BN=64, BK=32, 256 threads, 8x4/thread.
// grid.y slabs: [0, C/64) -> W1/Ybf, [C/64, 2C/64) -> W2/Yf.
template <int IN, int C>
__global__ __launch_bounds__(256) void gemm_rb(
    const float* __restrict__ X, const float* __restrict__ W1,
    const float* __restrict__ W2, unsigned short* __restrict__ Ybf,
    float* __restrict__ Yf, int n) {
    constexpr int BM = 128, BN = 64, BK = 32;
    constexpr int NB1 = C / BN;
    __shared__ float Xs[BK][BM + 4];
    __shared__ float Ws[BK][BN + 4];
    const int t = threadIdx.x;
    const int row0 = blockIdx.x * BM;
    const int slab = blockIdx.y;
    const bool bfout = (slab < NB1);
    const float* __restrict__ W = bfout ? W1 : W2;
    const int colbase = (slab % NB1) * BN;

    const int tx = t & 15, ty = t >> 4;
    const int n0 = tx * 4, m0 = ty * 8;

    float acc[8][4];
#pragma unroll
    for (int r = 0; r < 8; ++r)
#pragma unroll
        for (int q = 0; q < 4; ++q) acc[r][q] = 0.f;

    for (int k0 = 0; k0 < IN; k0 += BK) {
#pragma unroll
        for (int j = 0; j < 4; ++j) {
            const int c = t + 256 * j;
            const int m = c >> 3, kq = (c & 7) * 4;
            const int gr = row0 + m;
            float4 v = {0.f, 0.f, 0.f, 0.f};
            if (gr < n)
                v = *reinterpret_cast<const float4*>(&X[(size_t)gr * IN + k0 + kq]);
            Xs[kq + 0][m] = v.x;
            Xs[kq + 1][m] = v.y;
            Xs[kq + 2][m] = v.z;
            Xs[kq + 3][m] = v.w;
        }
#pragma unroll
        for (int j = 0; j < (BK * BN / 4) / 256; ++j) {
            const int c = t + 256 * j;
            const int k = c / (BN / 4), nq = (c % (BN / 4)) * 4;
            *reinterpret_cast<float4*>(&Ws[k][nq]) =
                *reinterpret_cast<const float4*>(&W[(size_t)(k0 + k) * C + colbase + nq]);
        }
        __syncthreads();
#pragma unroll 8
        for (int k = 0; k < BK; ++k) {
            const float4 b = *reinterpret_cast<const float4*>(&Ws[k][n0]);
            const float4 a0 = *reinterpret_cast<const float4*>(&Xs[k][m0]);
            const float4 a1 = *reinterpret_cast<const float4*>(&Xs[k][m0 + 4]);
            const float av[8] = {a0.x, a0.y, a0.z, a0.w, a1.x, a1.y, a1.z, a1.w};
            const float bv[4] = {b.x, b.y, b.z, b.w};
#pragma unroll
            for (int r = 0; r < 8; ++r)
#pragma unroll
                for (int q = 0; q < 4; ++q) acc[r][q] = fmaf(av[r], bv[q], acc[r][q]);
        }
        __syncthreads();
    }
    if (bfout) {
#pragma unroll
        for (int r = 0; r < 8; ++r) {
            const int gr = row0 + m0 + r;
            if (gr < n) {
                ushort4 o;
                o.x = f2bf(acc[r][0]);
                o.y = f2bf(acc[r][1]);
                o.z = f2bf(acc[r][2]);
                o.w = f2bf(acc[r][3]);
                *reinterpret_cast<ushort4*>(&Ybf[(size_t)gr * C + colbase + n0]) = o;
            }
        }
    } else {
#pragma unroll
        for (int r = 0; r < 8; ++r) {
            const int gr = row0 + m0 + r;
            if (gr < n) {
                const float4 o = {acc[r][0], acc[r][1], acc[r][2], acc[r][3]};
                *reinterpret_cast<float4*>(&Yf[(size_t)gr * C + colbase + n0]) = o;
            }
        }
    }
}

// ---------- CSR build ----------
__global__ __launch_bounds__(256) void count_k(const int* __restrict__ dsts,
                                               int* __restrict__ cnt, int e0) {
    for (int i = blockIdx.x * blockDim.x + threadIdx.x; i < e0;
         i += gridDim.x * blockDim.x)
        atomicAdd(&cnt[dsts[i]], 1);
}

__global__ __launch_bounds__(256) void bsum_k(const int* __restrict__ cnt,
                                              int* __restrict__ bsum, int n) {
    __shared__ int red[256];
    const int t = threadIdx.x;
    const int i = blockIdx.x * 256 + t;
    red[t] = (i < n) ? cnt[i] + 1 : 0;
    __syncthreads();
#pragma unroll
    for (int s = 128; s > 0; s >>= 1) {
        if (t < s) red[t] += red[t + s];
        __syncthreads();
    }
    if (t == 0) bsum[blockIdx.x] = red[0];
}

// Requires nblocks <= 256 (n <= 65536).
__global__ __launch_bounds__(256) void scan2_k(const int* __restrict__ cnt,
                                               const int* __restrict__ bsum,
                                               int* __restrict__ row_ptr, int n) {
    __shared__ int red[256];
    const int b = blockIdx.x, t = threadIdx.x;
    red[t] = (t < b) ? bsum[t] : 0;
    __syncthreads();
#pragma unroll
    for (int s = 128; s > 0; s >>= 1) {
        if (t < s) red[t] += red[t + s];
        __syncthreads();
    }
    const int offset = red[0];
    __syncthreads();
    const int i = b * 256 + t;
    const int x = (i < n) ? cnt[i] + 1 : 0;
    red[t] = x;
    __syncthreads();
#pragma unroll
    for (int s = 1; s < 256; s <<= 1) {
        const int add = (t >= s) ? red[t - s] : 0;
        __syncthreads();
        red[t] += add;
        __syncthreads();
    }
    if (i < n) row_ptr[i] = offset + red[t] - x;
    if (i == n - 1) row_ptr[n] = offset + red[t];
}

__global__ __launch_bounds__(256) void fill_k(
    const int* __restrict__ srcs, const int* __restrict__ dsts,
    const int* __restrict__ row_ptr, int* __restrict__ cursor,
    int* __restrict__ csr_src, int e0, int etot) {
    for (int i = blockIdx.x * blockDim.x + threadIdx.x; i < etot;
         i += gridDim.x * blockDim.x) {
        int s, d;
        if (i < e0) { s = srcs[i]; d = dsts[i]; } else { s = d = i - e0; }
        int pos = atomicAdd(&cursor[d], 1);
        csr_src[row_ptr[d] + pos] = s;
    }
}

// ---------- fused per-dst softmax aggregation, H=2 (HC=128, xl in bf16) ----------
// one wave per dst; 2 edge-groups x 32 lanes; unroll-2 with dual loads.
__global__ __launch_bounds__(256) void gat_dst2_k(
    const unsigned short* __restrict__ xl, const float* __restrict__ xr,
    const int* __restrict__ row_ptr, const int* __restrict__ csr_src,
    const float* __restrict__ att, const float* __restrict__ bias,
    float* __restrict__ out, int n) {
    const int lane = threadIdx.x & 63;
    const int g = lane >> 5, l32 = lane & 31;
    const int d = (blockIdx.x * blockDim.x + threadIdx.x) >> 6;
    if (d >= n) return;

    const float4 xrv = reinterpret_cast<const float4*>(xr + (size_t)d * 128)[l32];
    const float4 atv = reinterpret_cast<const float4*>(att)[l32];
    const int rp0 = row_ptr[d], rp1 = row_ptr[d + 1];

    float s = 0.f;
    float4 acc = {0.f, 0.f, 0.f, 0.f};
    int i = rp0 + g;
    for (; i + 2 < rp1; i += 4) {
        const int s0 = csr_src[i];
        const int s1 = csr_src[i + 2];
        const float4 a0 = bf4_to_f4(reinterpret_cast<const ushort4*>(xl + (size_t)s0 * 128)[l32]);
        const float4 a1 = bf4_to_f4(reinterpret_cast<const ushort4*>(xl + (size_t)s1 * 128)[l32]);
        float v, p0 = 0.f, p1 = 0.f;
        v = a0.x + xrv.x; p0 = fmaf(atv.x, (v > 0.f ? v : 0.2f * v), p0);
        v = a0.y + xrv.y; p0 = fmaf(atv.y, (v > 0.f ? v : 0.2f * v), p0);
        v = a0.z + xrv.z; p0 = fmaf(atv.z, (v > 0.f ? v : 0.2f * v), p0);
        v = a0.w + xrv.w; p0 = fmaf(atv.w, (v > 0.f ? v : 0.2f * v), p0);
        v = a1.x + xrv.x; p1 = fmaf(atv.x, (v > 0.f ? v : 0.2f * v), p1);
        v = a1.y + xrv.y; p1 = fmaf(atv.y, (v > 0.f ? v : 0.2f * v), p1);
        v = a1.z + xrv.z; p1 = fmaf(atv.z, (v > 0.f ? v : 0.2f * v), p1);
        v = a1.w + xrv.w; p1 = fmaf(atv.w, (v > 0.f ? v : 0.2f * v), p1);
#pragma unroll
        for (int msk = 8; msk >= 1; msk >>= 1) {
            p0 += __shfl_xor(p0, msk, 64);
            p1 += __shfl_xor(p1, msk, 64);
        }
        const float w0 = __expf(p0), w1 = __expf(p1);
        s += w0 + w1;
        acc.x = fmaf(w0, a0.x, fmaf(w1, a1.x, acc.x));
        acc.y = fmaf(w0, a0.y, fmaf(w1, a1.y, acc.y));
        acc.z = fmaf(w0, a0.z, fmaf(w1, a1.z, acc.z));
        acc.w = fmaf(w0, a0.w, fmaf(w1, a1.w, acc.w));
    }
    if (i < rp1) {
        const int s0 = csr_src[i];
        const float4 a0 = bf4_to_f4(reinterpret_cast<const ushort4*>(xl + (size_t)s0 * 128)[l32]);
        float v, p0 = 0.f;
        v = a0.x + xrv.x; p0 = fmaf(atv.x, (v > 0.f ? v : 0.2f * v), p0);
        v = a0.y + xrv.y; p0 = fmaf(atv.y, (v > 0.f ? v : 0.2f * v), p0);
        v = a0.z + xrv.z; p0 = fmaf(atv.z, (v > 0.f ? v : 0.2f * v), p0);
        v = a0.w + xrv.w; p0 = fmaf(atv.w, (v > 0.f ? v : 0.2f * v), p0);
#pragma unroll
        for (int msk = 8; msk >= 1; msk >>= 1) p0 += __shfl_xor(p0, msk, 64);
        const float w0 = __expf(p0);
        s += w0;
        acc.x = fmaf(w0, a0.x, acc.x);
        acc.y = fmaf(w0, a0.y, acc.y);
        acc.z = fmaf(w0, a0.z, acc.z);
        acc.w = fmaf(w0, a0.w, acc.w);
    }
    s += __shfl_xor(s, 32, 64);
    acc.x += __shfl_xor(acc.x, 32, 64);
    acc.y += __shfl_xor(acc.y, 32, 64);
    acc.z += __shfl_xor(acc.z, 32, 64);
    acc.w += __shfl_xor(acc.w, 32, 64);
    if (g == 0) {
        const float inv = 1.f / (s + 1e-16f);
        const float4 bv = reinterpret_cast<const float4*>(bias)[l32];
        float4 o;
        o.x = fmaxf(fmaf(acc.x, inv, bv.x), 0.f);
        o.y = fmaxf(fmaf(acc.y, inv, bv.y), 0.f);
        o.z = fmaxf(fmaf(acc.z, inv, bv.z), 0.f);
        o.w = fmaxf(fmaf(acc.w, inv, bv.w), 0.f);
        reinterpret_cast<float4*>(out + (size_t)d * 128)[l32] = o;
    }
}

// ---------- fused per-dst softmax aggregation, H=1 (C=64, xl in bf16) ----------
// one wave per dst; 4 edge-groups x 16 lanes; unroll-2 with dual loads.
__global__ __launch_bounds__(256) void gat_dst1_k(
    const unsigned short* __restrict__ xl, const float* __restrict__ xr,
    const int* __restrict__ row_ptr, const int* __restrict__ csr_src,
    const float* __restrict__ att, const float* __restrict__ bias,
    float* __restrict__ out, int n) {
    const int lane = threadIdx.x & 63;
    const int g = lane >> 4, l16 = lane & 15;
    const int d = (blockIdx.x * blockDim.x + threadIdx.x) >> 6;
    if (d >= n) return;

    const float4 xrv = reinterpret_cast<const float4*>(xr + (size_t)d * 64)[l16];
    const float4 atv = reinterpret_cast<const float4*>(att)[l16];
    const int rp0 = row_ptr[d], rp1 = row_ptr[d + 1];

    float s = 0.f;
    float4 acc = {0.f, 0.f, 0.f, 0.f};
    int i = rp0 + g;
    for (; i + 4 < rp1; i += 8) {
        const int s0 = csr_src[i];
        const int s1 = csr_src[i + 4];
        const float4 a0 = bf4_to_f4(reinterpret_cast<const ushort4*>(xl + (size_t)s0 * 64)[l16]);
        const float4 a1 = bf4_to_f4(reinterpret_cast<const ushort4*>(xl + (size_t)s1 * 64)[l16]);
        float v, p0 = 0.f, p1 = 0.f;
        v = a0.x + xrv.x; p0 = fmaf(atv.x, (v > 0.f ? v : 0.2f * v), p0);
        v = a0.y + xrv.y; p0 = fmaf(atv.y, (v > 0.f ? v : 0.2f * v), p0);
        v = a0.z + xrv.z; p0 = fmaf(atv.z, (v > 0.f ? v : 0.2f * v), p0);
        v = a0.w + xrv.w; p0 = fmaf(atv.w, (v > 0.f ? v : 0.2f * v), p0);
        v = a1.x + xrv.x; p1 = fmaf(atv.x, (v > 0.f ? v : 0.2f * v), p1);
        v = a1.y + xrv.y; p1 = fmaf(atv.y, (v > 0.f ? v : 0.2f * v), p1);
        v = a1.z + xrv.z; p1 = fmaf(atv.z, (v > 0.f ? v : 0.2f * v), p1);
        v = a1.w + xrv.w; p1 = fmaf(atv.w, (v > 0.f ? v : 0.2f * v), p1);
#pragma unroll
        for (int msk = 8; msk >= 1; msk >>= 1) {
            p0 += __shfl_xor(p0, msk, 64);
            p1 += __shfl_xor(p1, msk, 64);
        }
        const float w0 = __expf(p0), w1 = __expf(p1);
        s += w0 + w1;
        acc.x = fmaf(w0, a0.x, fmaf(w1, a1.x, acc.x));
        acc.y = fmaf(w0, a0.y, fmaf(w1, a1.y, acc.y));
        acc.z = fmaf(w0, a0.z, fmaf(w1, a1.z, acc.z));
        acc.w = fmaf(w0, a0.w, fmaf(w1, a1.w, acc.w));
    }
    if (i < rp1) {
        const int s0 = csr_src[i];
        const float4 a0 = bf4_to_f4(reinterpret_cast<const ushort4*>(xl + (size_t)s0 * 64)[l16]);
        float v, p0 = 0.f;
        v = a0.x + xrv.x; p0 = fmaf(atv.x, (v > 0.f ? v : 0.2f * v), p0);
        v = a0.y + xrv.y; p0 = fmaf(atv.y, (v > 0.f ? v : 0.2f * v), p0);
        v = a0.z + xrv.z; p0 = fmaf(atv.z, (v > 0.f ? v : 0.2f * v), p0);
        v = a0.w + xrv.w; p0 = fmaf(atv.w, (v > 0.f ? v : 0.2f * v), p0);
#pragma unroll
        for (int msk = 8; msk >= 1; msk >>= 1) p0 += __shfl_xor(p0, msk, 64);
        const float w0 = __expf(p0);
        s += w0;
        acc.x = fmaf(w0, a0.x, acc.x);
        acc.y = fmaf(w0, a0.y, acc.y);
        acc.z = fmaf(w0, a0.z, acc.z);
        acc.w = fmaf(w0, a0.w, acc.w);
    }
#pragma unroll
    for (int off = 16; off <= 32; off <<= 1) {
        s += __shfl_xor(s, off, 64);
        acc.x += __shfl_xor(acc.x, off, 64);
        acc.y += __shfl_xor(acc.y, off, 64);
        acc.z += __shfl_xor(acc.z, off, 64);
        acc.w += __shfl_xor(acc.w, off, 64);
    }
    if (g == 0) {
        const float inv = 1.f / (s + 1e-16f);
        const float4 bv = reinterpret_cast<const float4*>(bias)[l16];
        float4 o;
        o.x = fmaxf(fmaf(acc.x, inv, bv.x), 0.f);
        o.y = fmaxf(fmaf(acc.y, inv, bv.y), 0.f);
        o.z = fmaxf(fmaf(acc.z, inv, bv.z), 0.f);
        o.w = fmaxf(fmaf(acc.w, inv, bv.w), 0.f);
        reinterpret_cast<float4*>(out + (size_t)d * 64)[l16] = o;
    }
}

extern "C" void kernel_launch(void* const* d_in, const int* in_sizes, int n_in,
                              void* d_out, int out_size, void* d_ws, size_t ws_size,
                              hipStream_t stream) {
    const float* x    = (const float*)d_in[0];
    const int*   ei   = (const int*)d_in[1];
    const float* Wl1  = (const float*)d_in[2];
    const float* Wr1  = (const float*)d_in[3];
    const float* att1 = (const float*)d_in[4];
    const float* b1   = (const float*)d_in[5];
    const float* Wl2  = (const float*)d_in[6];
    const float* Wr2  = (const float*)d_in[7];
    const float* att2 = (const float*)d_in[8];
    const float* b2   = (const float*)d_in[9];

    const int n    = in_sizes[0] / 128;   // 50000
    const int e0   = in_sizes[1] / 2;     // 800000
    const int etot = e0 + n;
    const int* srcs = ei;
    const int* dsts = ei + e0;

    float* ws = (float*)d_ws;
    unsigned short* xlbf = (unsigned short*)ws;   // n*128 bf16 (= n*64 f32 slots)
    float* xr = ws + (size_t)n * 64;              // n*128 f32
    float* h1 = xr + (size_t)n * 128;             // n*128 f32
    int* row_ptr = (int*)(h1 + (size_t)n * 128);  // n+1
    int* cnt     = row_ptr + (n + 1);             // n (reused as cursor)
    int* bsum    = cnt + n;                       // <=256
    int* csr_src = bsum + 256;                    // etot

    const int nb = (n + 255) / 256;  // 196 <= 256

    // ---- CSR build (graph identical for both layers) ----
    hipMemsetAsync(cnt, 0, (size_t)n * sizeof(int), stream);
    count_k<<<2048, 256, 0, stream>>>(dsts, cnt, e0);
    bsum_k<<<nb, 256, 0, stream>>>(cnt, bsum, n);
    scan2_k<<<nb, 256, 0, stream>>>(cnt, bsum, row_ptr, n);
    hipMemsetAsync(cnt, 0, (size_t)n * sizeof(int), stream);  // -> cursor
    fill_k<<<2048, 256, 0, stream>>>(srcs, dsts, row_ptr, cnt, csr_src, e0, etot);

    const int mb = (n + 127) / 128;  // 391

    // ---- layer 1 (H=2, C=128 per W) ----
    gemm_rb<128, 128><<<dim3(mb, 4), 256, 0, stream>>>(x, Wl1, Wr1, xlbf, xr, n);
    gat_dst2_k<<<(n + 3) / 4, 256, 0, stream>>>(xlbf, xr, row_ptr, csr_src, att1, b1, h1, n);

    // ---- layer 2 (H=1, C=64 per W) ----
    gemm_rb<128, 64><<<dim3(mb, 2), 256, 0, stream>>>(h1, Wl2, Wr2, xlbf, xr, n);
    gat_dst1_k<<<(n + 3) / 4, 256, 0, stream>>>(xlbf, xr, row_ptr, csr_src, att2, b2,
                                                (float*)d_out, n);
}

// Round 7
// 244.657 us; speedup vs baseline: 1.4162x; 1.1047x over previous
//
#include <hip/hip_runtime.h>
#include <math.h>

typedef unsigned short ush;
typedef short bf16x8 __attribute__((ext_vector_type(8)));
typedef float f32x4 __attribute__((ext_vector_type(4)));

// ---------- bf16 helpers ----------
__device__ __forceinline__ ush f2bf(float f) {
    unsigned u = __float_as_uint(f);
    u += 0x7FFFu + ((u >> 16) & 1u);
    return (ush)(u >> 16);
}
__device__ __forceinline__ float bf2f(ush u) {
    return __uint_as_float((unsigned)u << 16);
}
__device__ __forceinline__ float4 bf4_to_f4(ushort4 u) {
    float4 r;
    r.x = bf2f(u.x); r.y = bf2f(u.y); r.z = bf2f(u.z); r.w = bf2f(u.w);
    return r;
}

// ---------- split X into hi/lo bf16 ----------
__global__ __launch_bounds__(256) void prep_x_k(const float* __restrict__ x,
                                                ush* __restrict__ hi,
                                                ush* __restrict__ lo, int tot4) {
    for (int i = blockIdx.x * blockDim.x + threadIdx.x; i < tot4;
         i += gridDim.x * blockDim.x) {
        const float4 v = reinterpret_cast<const float4*>(x)[i];
        ushort4 h, l4;
        h.x = f2bf(v.x); l4.x = f2bf(v.x - bf2f(h.x));
        h.y = f2bf(v.y); l4.y = f2bf(v.y - bf2f(h.y));
        h.z = f2bf(v.z); l4.z = f2bf(v.z - bf2f(h.z));
        h.w = f2bf(v.w); l4.w = f2bf(v.w - bf2f(h.w));
        reinterpret_cast<ushort4*>(hi)[i] = h;
        reinterpret_cast<ushort4*>(lo)[i] = l4;
    }
}

// ---------- pack W into MFMA B-fragment order, hi/lo ----------
// frag ids: Wl1: 0..31 (C=128), Wr1: 32..63 (C=128), Wl2: 64..79 (C=64), Wr2: 80..95
// within a W: fid = ks*(C/16) + c16;  lane l reg j <- W[ks*32 + (l>>4)*8 + j][c16*16 + (l&15)]
__global__ __launch_bounds__(64) void prep_w_k(
    const float* __restrict__ Wl1, const float* __restrict__ Wr1,
    const float* __restrict__ Wl2, const float* __restrict__ Wr2,
    ush* __restrict__ wph, ush* __restrict__ wpl) {
    const int bid = blockIdx.x, l = threadIdx.x;
    const float* W;
    int C, fid;
    if (bid < 32)      { W = Wl1; C = 128; fid = bid; }
    else if (bid < 64) { W = Wr1; C = 128; fid = bid - 32; }
    else if (bid < 80) { W = Wl2; C = 64;  fid = bid - 64; }
    else               { W = Wr2; C = 64;  fid = bid - 80; }
    const int nc16 = C / 16;
    const int ks = fid / nc16, c16 = fid % nc16;
#pragma unroll
    for (int j = 0; j < 8; ++j) {
        const int k = ks * 32 + (l >> 4) * 8 + j;
        const int c = c16 * 16 + (l & 15);
        const float v = W[(size_t)k * C + c];
        const ush h = f2bf(v);
        wph[(size_t)(bid * 64 + l) * 8 + j] = h;
        wpl[(size_t)(bid * 64 + l) * 8 + j] = f2bf(v - bf2f(h));
    }
}

// ---------- MFMA GEMM: Ybf = X@W1 (bf16 out), Yf = X@W2 (fp32 out) ----------
// X given as hi/lo bf16 [n][128]; W pre-packed fragments. No LDS, no barriers.
// grid: (ceil(n/64), 2*CW/64). 4 waves/block, one 16-row stripe each.
template <int CW>
__global__ __launch_bounds__(256) void gemm_mfma_k(
    const ush* __restrict__ xhi, const ush* __restrict__ xlo,
    const ush* __restrict__ wh1, const ush* __restrict__ wl1,
    const ush* __restrict__ wh2, const ush* __restrict__ wl2,
    ush* __restrict__ ybf, float* __restrict__ yf, int n) {
    constexpr int NC16 = CW / 16;
    constexpr int SPW = CW / 64;  // slabs per W
    const int l = threadIdx.x & 63;
    const int w = threadIdx.x >> 6;
    const int r0 = blockIdx.x * 64 + w * 16;
    const int slab = blockIdx.y;
    const bool isW1 = slab < SPW;
    const int slab_local = isW1 ? slab : slab - SPW;
    const ush* __restrict__ wh = isW1 ? wh1 : wh2;
    const ush* __restrict__ wl = isW1 ? wl1 : wl2;

    const int arow = min(r0 + (l & 15), n - 1);
    const int kb = (l >> 4) * 8;
    bf16x8 ah[4], al[4];
#pragma unroll
    for (int ks = 0; ks < 4; ++ks) {
        ah[ks] = *reinterpret_cast<const bf16x8*>(xhi + (size_t)arow * 128 + ks * 32 + kb);
        al[ks] = *reinterpret_cast<const bf16x8*>(xlo + (size_t)arow * 128 + ks * 32 + kb);
    }
    const int drow = (l >> 4) * 4;
    const int dcol = l & 15;
#pragma unroll
    for (int c16 = 0; c16 < 4; ++c16) {
        f32x4 acc = {0.f, 0.f, 0.f, 0.f};
#pragma unroll
        for (int ks = 0; ks < 4; ++ks) {
            const int fid = ks * NC16 + slab_local * 4 + c16;
            const bf16x8 bh = *reinterpret_cast<const bf16x8*>(wh + (size_t)(fid * 64 + l) * 8);
            const bf16x8 bl = *reinterpret_cast<const bf16x8*>(wl + (size_t)(fid * 64 + l) * 8);
            acc = __builtin_amdgcn_mfma_f32_16x16x32_bf16(ah[ks], bh, acc, 0, 0, 0);
            acc = __builtin_amdgcn_mfma_f32_16x16x32_bf16(al[ks], bh, acc, 0, 0, 0);
            acc = __builtin_amdgcn_mfma_f32_16x16x32_bf16(ah[ks], bl, acc, 0, 0, 0);
        }
        const int cg = slab_local * 64 + c16 * 16 + dcol;
#pragma unroll
        for (int q = 0; q < 4; ++q) {
            const int gr = r0 + drow + q;
            if (gr < n) {
                if (isW1) ybf[(size_t)gr * CW + cg] = f2bf(acc[q]);
                else      yf[(size_t)gr * CW + cg] = acc[q];
            }
        }
    }
}

// ---------- CSR build ----------
__global__ __launch_bounds__(256) void count_k(const int* __restrict__ dsts,
                                               int* __restrict__ cnt, int e0) {
    for (int i = blockIdx.x * blockDim.x + threadIdx.x; i < e0;
         i += gridDim.x * blockDim.x)
        atomicAdd(&cnt[dsts[i]], 1);
}

__global__ __launch_bounds__(256) void bsum_k(const int* __restrict__ cnt,
                                              int* __restrict__ bsum, int n) {
    __shared__ int red[256];
    const int t = threadIdx.x;
    const int i = blockIdx.x * 256 + t;
    red[t] = (i < n) ? cnt[i] + 1 : 0;
    __syncthreads();
#pragma unroll
    for (int s = 128; s > 0; s >>= 1) {
        if (t < s) red[t] += red[t + s];
        __syncthreads();
    }
    if (t == 0) bsum[blockIdx.x] = red[0];
}

// Requires nblocks <= 256 (n <= 65536).
__global__ __launch_bounds__(256) void scan2_k(const int* __restrict__ cnt,
                                               const int* __restrict__ bsum,
                                               int* __restrict__ row_ptr, int n) {
    __shared__ int red[256];
    const int b = blockIdx.x, t = threadIdx.x;
    red[t] = (t < b) ? bsum[t] : 0;
    __syncthreads();
#pragma unroll
    for (int s = 128; s > 0; s >>= 1) {
        if (t < s) red[t] += red[t + s];
        __syncthreads();
    }
    const int offset = red[0];
    __syncthreads();
    const int i = b * 256 + t;
    const int x = (i < n) ? cnt[i] + 1 : 0;
    red[t] = x;
    __syncthreads();
#pragma unroll
    for (int s = 1; s < 256; s <<= 1) {
        const int add = (t >= s) ? red[t - s] : 0;
        __syncthreads();
        red[t] += add;
        __syncthreads();
    }
    if (i < n) row_ptr[i] = offset + red[t] - x;
    if (i == n - 1) row_ptr[n] = offset + red[t];
}

__global__ __launch_bounds__(256) void fill_k(
    const int* __restrict__ srcs, const int* __restrict__ dsts,
    const int* __restrict__ row_ptr, int* __restrict__ cursor,
    int* __restrict__ csr_src, int e0, int etot) {
    for (int i = blockIdx.x * blockDim.x + threadIdx.x; i < etot;
         i += gridDim.x * blockDim.x) {
        int s, d;
        if (i < e0) { s = srcs[i]; d = dsts[i]; } else { s = d = i - e0; }
        int pos = atomicAdd(&cursor[d], 1);
        csr_src[row_ptr[d] + pos] = s;
    }
}

// ---------- fused per-dst softmax aggregation, H=2 (HC=128, xl bf16) ----------
// writes h1 as hi/lo bf16 pair (layer-2 GEMM input)
__global__ __launch_bounds__(256) void gat_dst2_k(
    const ush* __restrict__ xl, const float* __restrict__ xr,
    const int* __restrict__ row_ptr, const int* __restrict__ csr_src,
    const float* __restrict__ att, const float* __restrict__ bias,
    ush* __restrict__ h1hi, ush* __restrict__ h1lo, int n) {
    const int lane = threadIdx.x & 63;
    const int g = lane >> 5, l32 = lane & 31;
    const int d = (blockIdx.x * blockDim.x + threadIdx.x) >> 6;
    if (d >= n) return;

    const float4 xrv = reinterpret_cast<const float4*>(xr + (size_t)d * 128)[l32];
    const float4 atv = reinterpret_cast<const float4*>(att)[l32];
    const int rp0 = row_ptr[d], rp1 = row_ptr[d + 1];

    float s = 0.f;
    float4 acc = {0.f, 0.f, 0.f, 0.f};
    int i = rp0 + g;
    for (; i + 2 < rp1; i += 4) {
        const int s0 = csr_src[i];
        const int s1 = csr_src[i + 2];
        const float4 a0 = bf4_to_f4(reinterpret_cast<const ushort4*>(xl + (size_t)s0 * 128)[l32]);
        const float4 a1 = bf4_to_f4(reinterpret_cast<const ushort4*>(xl + (size_t)s1 * 128)[l32]);
        float v, p0 = 0.f, p1 = 0.f;
        v = a0.x + xrv.x; p0 = fmaf(atv.x, (v > 0.f ? v : 0.2f * v), p0);
        v = a0.y + xrv.y; p0 = fmaf(atv.y, (v > 0.f ? v : 0.2f * v), p0);
        v = a0.z + xrv.z; p0 = fmaf(atv.z, (v > 0.f ? v : 0.2f * v), p0);
        v = a0.w + xrv.w; p0 = fmaf(atv.w, (v > 0.f ? v : 0.2f * v), p0);
        v = a1.x + xrv.x; p1 = fmaf(atv.x, (v > 0.f ? v : 0.2f * v), p1);
        v = a1.y + xrv.y; p1 = fmaf(atv.y, (v > 0.f ? v : 0.2f * v), p1);
        v = a1.z + xrv.z; p1 = fmaf(atv.z, (v > 0.f ? v : 0.2f * v), p1);
        v = a1.w + xrv.w; p1 = fmaf(atv.w, (v > 0.f ? v : 0.2f * v), p1);
#pragma unroll
        for (int msk = 8; msk >= 1; msk >>= 1) {
            p0 += __shfl_xor(p0, msk, 64);
            p1 += __shfl_xor(p1, msk, 64);
        }
        const float w0 = __expf(p0), w1 = __expf(p1);
        s += w0 + w1;
        acc.x = fmaf(w0, a0.x, fmaf(w1, a1.x, acc.x));
        acc.y = fmaf(w0, a0.y, fmaf(w1, a1.y, acc.y));
        acc.z = fmaf(w0, a0.z, fmaf(w1, a1.z, acc.z));
        acc.w = fmaf(w0, a0.w, fmaf(w1, a1.w, acc.w));
    }
    if (i < rp1) {
        const int s0 = csr_src[i];
        const float4 a0 = bf4_to_f4(reinterpret_cast<const ushort4*>(xl + (size_t)s0 * 128)[l32]);
        float v, p0 = 0.f;
        v = a0.x + xrv.x; p0 = fmaf(atv.x, (v > 0.f ? v : 0.2f * v), p0);
        v = a0.y + xrv.y; p0 = fmaf(atv.y, (v > 0.f ? v : 0.2f * v), p0);
        v = a0.z + xrv.z; p0 = fmaf(atv.z, (v > 0.f ? v : 0.2f * v), p0);
        v = a0.w + xrv.w; p0 = fmaf(atv.w, (v > 0.f ? v : 0.2f * v), p0);
#pragma unroll
        for (int msk = 8; msk >= 1; msk >>= 1) p0 += __shfl_xor(p0, msk, 64);
        const float w0 = __expf(p0);
        s += w0;
        acc.x = fmaf(w0, a0.x, acc.x);
        acc.y = fmaf(w0, a0.y, acc.y);
        acc.z = fmaf(w0, a0.z, acc.z);
        acc.w = fmaf(w0, a0.w, acc.w);
    }
    s += __shfl_xor(s, 32, 64);
    acc.x += __shfl_xor(acc.x, 32, 64);
    acc.y += __shfl_xor(acc.y, 32, 64);
    acc.z += __shfl_xor(acc.z, 32, 64);
    acc.w += __shfl_xor(acc.w, 32, 64);
    if (g == 0) {
        const float inv = 1.f / (s + 1e-16f);
        const float4 bv = reinterpret_cast<const float4*>(bias)[l32];
        float4 o;
        o.x = fmaxf(fmaf(acc.x, inv, bv.x), 0.f);
        o.y = fmaxf(fmaf(acc.y, inv, bv.y), 0.f);
        o.z = fmaxf(fmaf(acc.z, inv, bv.z), 0.f);
        o.w = fmaxf(fmaf(acc.w, inv, bv.w), 0.f);
        ushort4 hh, ll;
        hh.x = f2bf(o.x); ll.x = f2bf(o.x - bf2f(hh.x));
        hh.y = f2bf(o.y); ll.y = f2bf(o.y - bf2f(hh.y));
        hh.z = f2bf(o.z); ll.z = f2bf(o.z - bf2f(hh.z));
        hh.w = f2bf(o.w); ll.w = f2bf(o.w - bf2f(hh.w));
        reinterpret_cast<ushort4*>(h1hi + (size_t)d * 128)[l32] = hh;
        reinterpret_cast<ushort4*>(h1lo + (size_t)d * 128)[l32] = ll;
    }
}

// ---------- fused per-dst softmax aggregation, H=1 (C=64, xl bf16) ----------
__global__ __launch_bounds__(256) void gat_dst1_k(
    const ush* __restrict__ xl, const float* __restrict__ xr,
    const int* __restrict__ row_ptr, const int* __restrict__ csr_src,
    const float* __restrict__ att, const float* __restrict__ bias,
    float* __restrict__ out, int n) {
    const int lane = threadIdx.x & 63;
    const int g = lane >> 4, l16 = lane & 15;
    const int d = (blockIdx.x * blockDim.x + threadIdx.x) >> 6;
    if (d >= n) return;

    const float4 xrv = reinterpret_cast<const float4*>(xr + (size_t)d * 64)[l16];
    const float4 atv = reinterpret_cast<const float4*>(att)[l16];
    const int rp0 = row_ptr[d], rp1 = row_ptr[d + 1];

    float s = 0.f;
    float4 acc = {0.f, 0.f, 0.f, 0.f};
    int i = rp0 + g;
    for (; i + 4 < rp1; i += 8) {
        const int s0 = csr_src[i];
        const int s1 = csr_src[i + 4];
        const float4 a0 = bf4_to_f4(reinterpret_cast<const ushort4*>(xl + (size_t)s0 * 64)[l16]);
        const float4 a1 = bf4_to_f4(reinterpret_cast<const ushort4*>(xl + (size_t)s1 * 64)[l16]);
        float v, p0 = 0.f, p1 = 0.f;
        v = a0.x + xrv.x; p0 = fmaf(atv.x, (v > 0.f ? v : 0.2f * v), p0);
        v = a0.y + xrv.y; p0 = fmaf(atv.y, (v > 0.f ? v : 0.2f * v), p0);
        v = a0.z + xrv.z; p0 = fmaf(atv.z, (v > 0.f ? v : 0.2f * v), p0);
        v = a0.w + xrv.w; p0 = fmaf(atv.w, (v > 0.f ? v : 0.2f * v), p0);
        v = a1.x + xrv.x; p1 = fmaf(atv.x, (v > 0.f ? v : 0.2f * v), p1);
        v = a1.y + xrv.y; p1 = fmaf(atv.y, (v > 0.f ? v : 0.2f * v), p1);
        v = a1.z + xrv.z; p1 = fmaf(atv.z, (v > 0.f ? v : 0.2f * v), p1);
        v = a1.w + xrv.w; p1 = fmaf(atv.w, (v > 0.f ? v : 0.2f * v), p1);
#pragma unroll
        for (int msk = 8; msk >= 1; msk >>= 1) {
            p0 += __shfl_xor(p0, msk, 64);
            p1 += __shfl_xor(p1, msk, 64);
        }
        const float w0 = __expf(p0), w1 = __expf(p1);
        s += w0 + w1;
        acc.x = fmaf(w0, a0.x, fmaf(w1, a1.x, acc.x));
        acc.y = fmaf(w0, a0.y, fmaf(w1, a1.y, acc.y));
        acc.z = fmaf(w0, a0.z, fmaf(w1, a1.z, acc.z));
        acc.w = fmaf(w0, a0.w, fmaf(w1, a1.w, acc.w));
    }
    if (i < rp1) {
        const int s0 = csr_src[i];
        const float4 a0 = bf4_to_f4(reinterpret_cast<const ushort4*>(xl + (size_t)s0 * 64)[l16]);
        float v, p0 = 0.f;
        v = a0.x + xrv.x; p0 = fmaf(atv.x, (v > 0.f ? v : 0.2f * v), p0);
        v = a0.y + xrv.y; p0 = fmaf(atv.y, (v > 0.f ? v : 0.2f * v), p0);
        v = a0.z + xrv.z; p0 = fmaf(atv.z, (v > 0.f ? v : 0.2f * v), p0);
        v = a0.w + xrv.w; p0 = fmaf(atv.w, (v > 0.f ? v : 0.2f * v), p0);
#pragma unroll
        for (int msk = 8; msk >= 1; msk >>= 1) p0 += __shfl_xor(p0, msk, 64);
        const float w0 = __expf(p0);
        s += w0;
        acc.x = fmaf(w0, a0.x, acc.x);
        acc.y = fmaf(w0, a0.y, acc.y);
        acc.z = fmaf(w0, a0.z, acc.z);
        acc.w = fmaf(w0, a0.w, acc.w);
    }
#pragma unroll
    for (int off = 16; off <= 32; off <<= 1) {
        s += __shfl_xor(s, off, 64);
        acc.x += __shfl_xor(acc.x, off, 64);
        acc.y += __shfl_xor(acc.y, off, 64);
        acc.z += __shfl_xor(acc.z, off, 64);
        acc.w += __shfl_xor(acc.w, off, 64);
    }
    if (g == 0) {
        const float inv = 1.f / (s + 1e-16f);
        const float4 bv = reinterpret_cast<const float4*>(bias)[l16];
        float4 o;
        o.x = fmaxf(fmaf(acc.x, inv, bv.x), 0.f);
        o.y = fmaxf(fmaf(acc.y, inv, bv.y), 0.f);
        o.z = fmaxf(fmaf(acc.z, inv, bv.z), 0.f);
        o.w = fmaxf(fmaf(acc.w, inv, bv.w), 0.f);
        reinterpret_cast<float4*>(out + (size_t)d * 64)[l16] = o;
    }
}

extern "C" void kernel_launch(void* const* d_in, const int* in_sizes, int n_in,
                              void* d_out, int out_size, void* d_ws, size_t ws_size,
                              hipStream_t stream) {
    const float* x    = (const float*)d_in[0];
    const int*   ei   = (const int*)d_in[1];
    const float* Wl1  = (const float*)d_in[2];
    const float* Wr1  = (const float*)d_in[3];
    const float* att1 = (const float*)d_in[4];
    const float* b1   = (const float*)d_in[5];
    const float* Wl2  = (const float*)d_in[6];
    const float* Wr2  = (const float*)d_in[7];
    const float* att2 = (const float*)d_in[8];
    const float* b2   = (const float*)d_in[9];

    const int n    = in_sizes[0] / 128;   // 50000
    const int e0   = in_sizes[1] / 2;     // 800000
    const int etot = e0 + n;
    const int* srcs = ei;
    const int* dsts = ei + e0;

    float* ws = (float*)d_ws;
    // [n*64] xhi (reused h1hi) | [n*64] xlo (reused h1lo) | [n*64] xlbf | [n*128] xr
    ush*   xhi  = (ush*)ws;                        // n*128 ush
    ush*   xlo  = (ush*)(ws + (size_t)n * 64);     // n*128 ush
    ush*   xlbf = (ush*)(ws + (size_t)n * 128);    // n*128 ush (L2 uses n*64)
    float* xr   = ws + (size_t)n * 192;            // n*128 f32
    int* row_ptr = (int*)(ws + (size_t)n * 320);   // n+1
    int* cnt     = row_ptr + (n + 1);              // n
    int* bsum    = cnt + n;                        // 256
    int* csr_src = bsum + 256;                     // etot
    ush* wph     = (ush*)(csr_src + etot);         // 96*512 ush
    ush* wpl     = wph + 96 * 512;                 // 96*512 ush

    const int nb = (n + 255) / 256;  // <= 256

    // ---- CSR build (graph identical for both layers) ----
    hipMemsetAsync(cnt, 0, (size_t)n * sizeof(int), stream);
    count_k<<<2048, 256, 0, stream>>>(dsts, cnt, e0);
    bsum_k<<<nb, 256, 0, stream>>>(cnt, bsum, n);
    scan2_k<<<nb, 256, 0, stream>>>(cnt, bsum, row_ptr, n);
    hipMemsetAsync(cnt, 0, (size_t)n * sizeof(int), stream);  // -> cursor
    fill_k<<<2048, 256, 0, stream>>>(srcs, dsts, row_ptr, cnt, csr_src, e0, etot);

    // ---- precision-split preps ----
    prep_w_k<<<96, 64, 0, stream>>>(Wl1, Wr1, Wl2, Wr2, wph, wpl);
    prep_x_k<<<2048, 256, 0, stream>>>(x, xhi, xlo, n * 32);

    const int gx = (n + 63) / 64;

    // ---- layer 1 (H=2): xl bf16 [n,128], xr f32 [n,128] ----
    gemm_mfma_k<128><<<dim3(gx, 4), 256, 0, stream>>>(
        xhi, xlo, wph, wpl, wph + 32 * 512, wpl + 32 * 512, xlbf, xr, n);
    gat_dst2_k<<<(n + 3) / 4, 256, 0, stream>>>(xlbf, xr, row_ptr, csr_src,
                                                att1, b1, xhi, xlo, n);

    // ---- layer 2 (H=1): xl2 bf16 [n,64], xr2 f32 [n,64] ----
    gemm_mfma_k<64><<<dim3(gx, 2), 256, 0, stream>>>(
        xhi, xlo, wph + 64 * 512, wpl + 64 * 512, wph + 80 * 512, wpl + 80 * 512,
        xlbf, xr, n);
    gat_dst1_k<<<(n + 3) / 4, 256, 0, stream>>>(xlbf, xr, row_ptr, csr_src,
                                                att2, b2, (float*)d_out, n);
}

// Round 8
// 198.212 us; speedup vs baseline: 1.7480x; 1.2343x over previous
//
#include <hip/hip_runtime.h>
#include <math.h>

typedef unsigned short ush;
typedef short bf16x8 __attribute__((ext_vector_type(8)));
typedef float f32x4 __attribute__((ext_vector_type(4)));

// ---------- bf16 helpers ----------
__device__ __forceinline__ ush f2bf(float f) {
    unsigned u = __float_as_uint(f);
    u += 0x7FFFu + ((u >> 16) & 1u);
    return (ush)(u >> 16);
}
__device__ __forceinline__ float bf2f(ush u) {
    return __uint_as_float((unsigned)u << 16);
}
__device__ __forceinline__ float4 bf4_to_f4(ushort4 u) {
    float4 r;
    r.x = bf2f(u.x); r.y = bf2f(u.y); r.z = bf2f(u.z); r.w = bf2f(u.w);
    return r;
}

// ---------- split X into hi/lo bf16 ----------
__global__ __launch_bounds__(256) void prep_x_k(const float* __restrict__ x,
                                                ush* __restrict__ hi,
                                                ush* __restrict__ lo, int tot4) {
    for (int i = blockIdx.x * blockDim.x + threadIdx.x; i < tot4;
         i += gridDim.x * blockDim.x) {
        const float4 v = reinterpret_cast<const float4*>(x)[i];
        ushort4 h, l4;
        h.x = f2bf(v.x); l4.x = f2bf(v.x - bf2f(h.x));
        h.y = f2bf(v.y); l4.y = f2bf(v.y - bf2f(h.y));
        h.z = f2bf(v.z); l4.z = f2bf(v.z - bf2f(h.z));
        h.w = f2bf(v.w); l4.w = f2bf(v.w - bf2f(h.w));
        reinterpret_cast<ushort4*>(hi)[i] = h;
        reinterpret_cast<ushort4*>(lo)[i] = l4;
    }
}

// ---------- pack W into MFMA B-fragment order, hi/lo ----------
__global__ __launch_bounds__(64) void prep_w_k(
    const float* __restrict__ Wl1, const float* __restrict__ Wr1,
    const float* __restrict__ Wl2, const float* __restrict__ Wr2,
    ush* __restrict__ wph, ush* __restrict__ wpl) {
    const int bid = blockIdx.x, l = threadIdx.x;
    const float* W;
    int C, fid;
    if (bid < 32)      { W = Wl1; C = 128; fid = bid; }
    else if (bid < 64) { W = Wr1; C = 128; fid = bid - 32; }
    else if (bid < 80) { W = Wl2; C = 64;  fid = bid - 64; }
    else               { W = Wr2; C = 64;  fid = bid - 80; }
    const int nc16 = C / 16;
    const int ks = fid / nc16, c16 = fid % nc16;
#pragma unroll
    for (int j = 0; j < 8; ++j) {
        const int k = ks * 32 + (l >> 4) * 8 + j;
        const int c = c16 * 16 + (l & 15);
        const float v = W[(size_t)k * C + c];
        const ush h = f2bf(v);
        wph[(size_t)(bid * 64 + l) * 8 + j] = h;
        wpl[(size_t)(bid * 64 + l) * 8 + j] = f2bf(v - bf2f(h));
    }
}

// ---------- MFMA GEMM ----------
template <int CW>
__global__ __launch_bounds__(256) void gemm_mfma_k(
    const ush* __restrict__ xhi, const ush* __restrict__ xlo,
    const ush* __restrict__ wh1, const ush* __restrict__ wl1,
    const ush* __restrict__ wh2, const ush* __restrict__ wl2,
    ush* __restrict__ ybf, float* __restrict__ yf, int n) {
    constexpr int NC16 = CW / 16;
    constexpr int SPW = CW / 64;
    const int l = threadIdx.x & 63;
    const int w = threadIdx.x >> 6;
    const int r0 = blockIdx.x * 64 + w * 16;
    const int slab = blockIdx.y;
    const bool isW1 = slab < SPW;
    const int slab_local = isW1 ? slab : slab - SPW;
    const ush* __restrict__ wh = isW1 ? wh1 : wh2;
    const ush* __restrict__ wl = isW1 ? wl1 : wl2;

    const int arow = min(r0 + (l & 15), n - 1);
    const int kb = (l >> 4) * 8;
    bf16x8 ah[4], al[4];
#pragma unroll
    for (int ks = 0; ks < 4; ++ks) {
        ah[ks] = *reinterpret_cast<const bf16x8*>(xhi + (size_t)arow * 128 + ks * 32 + kb);
        al[ks] = *reinterpret_cast<const bf16x8*>(xlo + (size_t)arow * 128 + ks * 32 + kb);
    }
    const int drow = (l >> 4) * 4;
    const int dcol = l & 15;
#pragma unroll
    for (int c16 = 0; c16 < 4; ++c16) {
        f32x4 acc = {0.f, 0.f, 0.f, 0.f};
#pragma unroll
        for (int ks = 0; ks < 4; ++ks) {
            const int fid = ks * NC16 + slab_local * 4 + c16;
            const bf16x8 bh = *reinterpret_cast<const bf16x8*>(wh + (size_t)(fid * 64 + l) * 8);
            const bf16x8 bl = *reinterpret_cast<const bf16x8*>(wl + (size_t)(fid * 64 + l) * 8);
            acc = __builtin_amdgcn_mfma_f32_16x16x32_bf16(ah[ks], bh, acc, 0, 0, 0);
            acc = __builtin_amdgcn_mfma_f32_16x16x32_bf16(al[ks], bh, acc, 0, 0, 0);
            acc = __builtin_amdgcn_mfma_f32_16x16x32_bf16(ah[ks], bl, acc, 0, 0, 0);
        }
        const int cg = slab_local * 64 + c16 * 16 + dcol;
#pragma unroll
        for (int q = 0; q < 4; ++q) {
            const int gr = r0 + drow + q;
            if (gr < n) {
                if (isW1) ybf[(size_t)gr * CW + cg] = f2bf(acc[q]);
                else      yf[(size_t)gr * CW + cg] = acc[q];
            }
        }
    }
}

// ================= CSR build via 2-level counting sort =================
// buckets of 128 dsts: b = d >> 7.  NB = ceil(n/128) <= 512.

__global__ __launch_bounds__(256) void hist_k(const int* __restrict__ dsts,
                                              int* __restrict__ ghist,
                                              int e0, int etot) {
    __shared__ int h[512];
    const int t = threadIdx.x;
    for (int i = t; i < 512; i += 256) h[i] = 0;
    __syncthreads();
    for (int i = blockIdx.x * blockDim.x + t; i < etot; i += gridDim.x * blockDim.x) {
        const int d = (i < e0) ? dsts[i] : (i - e0);
        atomicAdd(&h[d >> 7], 1);
    }
    __syncthreads();
    for (int i = t; i < 512; i += 256)
        if (h[i]) atomicAdd(&ghist[i], h[i]);
}

__global__ __launch_bounds__(512) void scanb_k(const int* __restrict__ ghist,
                                               int* __restrict__ boff,
                                               int* __restrict__ cur) {
    __shared__ int red[512];
    const int t = threadIdx.x;
    const int x = ghist[t];
    red[t] = x;
    __syncthreads();
#pragma unroll
    for (int s = 1; s < 512; s <<= 1) {
        const int add = (t >= s) ? red[t - s] : 0;
        __syncthreads();
        red[t] += add;
        __syncthreads();
    }
    const int excl = red[t] - x;
    boff[t] = excl;
    cur[t] = excl;
}

// each block: contiguous 2048-edge chunk -> bucket-ordered pairs via
// per-bucket contiguous runs (one global atomic per (block,bucket)).
__global__ __launch_bounds__(256) void semisort_k(
    const int* __restrict__ srcs, const int* __restrict__ dsts,
    int* __restrict__ cur, int2* __restrict__ pairs, int e0, int etot) {
    __shared__ int hist[512], gbase[512], lcur[512];
    const int t = threadIdx.x;
    const int start = blockIdx.x * 2048;
    const int end = min(start + 2048, etot);
    for (int i = t; i < 512; i += 256) { hist[i] = 0; lcur[i] = 0; }
    __syncthreads();
    for (int i = start + t; i < end; i += 256) {
        const int d = (i < e0) ? dsts[i] : (i - e0);
        atomicAdd(&hist[d >> 7], 1);
    }
    __syncthreads();
    for (int i = t; i < 512; i += 256) {
        const int c = hist[i];
        gbase[i] = c ? atomicAdd(&cur[i], c) : 0;
    }
    __syncthreads();
    for (int i = start + t; i < end; i += 256) {
        int s, d;
        if (i < e0) { s = srcs[i]; d = dsts[i]; } else { s = d = i - e0; }
        const int b = d >> 7;
        const int p = atomicAdd(&lcur[b], 1);
        int2 pr; pr.x = s; pr.y = d;
        pairs[gbase[b] + p] = pr;
    }
}

// one block per bucket: per-dst count -> scan -> row_ptr + csr_src fill.
__global__ __launch_bounds__(256) void bucket_fill_k(
    const int2* __restrict__ pairs, const int* __restrict__ boff,
    int* __restrict__ row_ptr, int* __restrict__ csr_src, int n, int etot) {
    __shared__ int cnt[128], cur[128];
    const int b = blockIdx.x, t = threadIdx.x;
    const int lo = boff[b], hi = boff[b + 1];
    if (t < 128) cnt[t] = 0;
    __syncthreads();
    for (int e = lo + t; e < hi; e += 256)
        atomicAdd(&cnt[pairs[e].y & 127], 1);
    __syncthreads();
    const int x = (t < 128) ? cnt[t] : 0;
#pragma unroll
    for (int s = 1; s < 128; s <<= 1) {
        const int add = (t < 128 && t >= s) ? cnt[t - s] : 0;
        __syncthreads();
        if (t < 128) cnt[t] += add;
        __syncthreads();
    }
    if (t < 128) {
        const int excl = cnt[t] - x;
        cur[t] = excl;
        const int d = b * 128 + t;
        if (d < n) row_ptr[d] = lo + excl;
    }
    if (b == 0 && t == 0) row_ptr[n] = etot;
    __syncthreads();
    for (int e = lo + t; e < hi; e += 256) {
        const int2 p = pairs[e];
        const int pos = atomicAdd(&cur[p.y & 127], 1);
        csr_src[lo + pos] = p.x;
    }
}

// ---------- fused per-dst softmax aggregation, H=2 (HC=128, xl bf16) ----------
__global__ __launch_bounds__(256) void gat_dst2_k(
    const ush* __restrict__ xl, const float* __restrict__ xr,
    const int* __restrict__ row_ptr, const int* __restrict__ csr_src,
    const float* __restrict__ att, const float* __restrict__ bias,
    ush* __restrict__ h1hi, ush* __restrict__ h1lo, int n) {
    const int lane = threadIdx.x & 63;
    const int g = lane >> 5, l32 = lane & 31;
    const int d = (blockIdx.x * blockDim.x + threadIdx.x) >> 6;
    if (d >= n) return;

    const float4 xrv = reinterpret_cast<const float4*>(xr + (size_t)d * 128)[l32];
    const float4 atv = reinterpret_cast<const float4*>(att)[l32];
    const int rp0 = row_ptr[d], rp1 = row_ptr[d + 1];

    float s = 0.f;
    float4 acc = {0.f, 0.f, 0.f, 0.f};
    int i = rp0 + g;
    for (; i + 2 < rp1; i += 4) {
        const int s0 = csr_src[i];
        const int s1 = csr_src[i + 2];
        const float4 a0 = bf4_to_f4(reinterpret_cast<const ushort4*>(xl + (size_t)s0 * 128)[l32]);
        const float4 a1 = bf4_to_f4(reinterpret_cast<const ushort4*>(xl + (size_t)s1 * 128)[l32]);
        float v, p0 = 0.f, p1 = 0.f;
        v = a0.x + xrv.x; p0 = fmaf(atv.x, (v > 0.f ? v : 0.2f * v), p0);
        v = a0.y + xrv.y; p0 = fmaf(atv.y, (v > 0.f ? v : 0.2f * v), p0);
        v = a0.z + xrv.z; p0 = fmaf(atv.z, (v > 0.f ? v : 0.2f * v), p0);
        v = a0.w + xrv.w; p0 = fmaf(atv.w, (v > 0.f ? v : 0.2f * v), p0);
        v = a1.x + xrv.x; p1 = fmaf(atv.x, (v > 0.f ? v : 0.2f * v), p1);
        v = a1.y + xrv.y; p1 = fmaf(atv.y, (v > 0.f ? v : 0.2f * v), p1);
        v = a1.z + xrv.z; p1 = fmaf(atv.z, (v > 0.f ? v : 0.2f * v), p1);
        v = a1.w + xrv.w; p1 = fmaf(atv.w, (v > 0.f ? v : 0.2f * v), p1);
#pragma unroll
        for (int msk = 8; msk >= 1; msk >>= 1) {
            p0 += __shfl_xor(p0, msk, 64);
            p1 += __shfl_xor(p1, msk, 64);
        }
        const float w0 = __expf(p0), w1 = __expf(p1);
        s += w0 + w1;
        acc.x = fmaf(w0, a0.x, fmaf(w1, a1.x, acc.x));
        acc.y = fmaf(w0, a0.y, fmaf(w1, a1.y, acc.y));
        acc.z = fmaf(w0, a0.z, fmaf(w1, a1.z, acc.z));
        acc.w = fmaf(w0, a0.w, fmaf(w1, a1.w, acc.w));
    }
    if (i < rp1) {
        const int s0 = csr_src[i];
        const float4 a0 = bf4_to_f4(reinterpret_cast<const ushort4*>(xl + (size_t)s0 * 128)[l32]);
        float v, p0 = 0.f;
        v = a0.x + xrv.x; p0 = fmaf(atv.x, (v > 0.f ? v : 0.2f * v), p0);
        v = a0.y + xrv.y; p0 = fmaf(atv.y, (v > 0.f ? v : 0.2f * v), p0);
        v = a0.z + xrv.z; p0 = fmaf(atv.z, (v > 0.f ? v : 0.2f * v), p0);
        v = a0.w + xrv.w; p0 = fmaf(atv.w, (v > 0.f ? v : 0.2f * v), p0);
#pragma unroll
        for (int msk = 8; msk >= 1; msk >>= 1) p0 += __shfl_xor(p0, msk, 64);
        const float w0 = __expf(p0);
        s += w0;
        acc.x = fmaf(w0, a0.x, acc.x);
        acc.y = fmaf(w0, a0.y, acc.y);
        acc.z = fmaf(w0, a0.z, acc.z);
        acc.w = fmaf(w0, a0.w, acc.w);
    }
    s += __shfl_xor(s, 32, 64);
    acc.x += __shfl_xor(acc.x, 32, 64);
    acc.y += __shfl_xor(acc.y, 32, 64);
    acc.z += __shfl_xor(acc.z, 32, 64);
    acc.w += __shfl_xor(acc.w, 32, 64);
    if (g == 0) {
        const float inv = 1.f / (s + 1e-16f);
        const float4 bv = reinterpret_cast<const float4*>(bias)[l32];
        float4 o;
        o.x = fmaxf(fmaf(acc.x, inv, bv.x), 0.f);
        o.y = fmaxf(fmaf(acc.y, inv, bv.y), 0.f);
        o.z = fmaxf(fmaf(acc.z, inv, bv.z), 0.f);
        o.w = fmaxf(fmaf(acc.w, inv, bv.w), 0.f);
        ushort4 hh, ll;
        hh.x = f2bf(o.x); ll.x = f2bf(o.x - bf2f(hh.x));
        hh.y = f2bf(o.y); ll.y = f2bf(o.y - bf2f(hh.y));
        hh.z = f2bf(o.z); ll.z = f2bf(o.z - bf2f(hh.z));
        hh.w = f2bf(o.w); ll.w = f2bf(o.w - bf2f(hh.w));
        reinterpret_cast<ushort4*>(h1hi + (size_t)d * 128)[l32] = hh;
        reinterpret_cast<ushort4*>(h1lo + (size_t)d * 128)[l32] = ll;
    }
}

// ---------- fused per-dst softmax aggregation, H=1 (C=64, xl bf16) ----------
__global__ __launch_bounds__(256) void gat_dst1_k(
    const ush* __restrict__ xl, const float* __restrict__ xr,
    const int* __restrict__ row_ptr, const int* __restrict__ csr_src,
    const float* __restrict__ att, const float* __restrict__ bias,
    float* __restrict__ out, int n) {
    const int lane = threadIdx.x & 63;
    const int g = lane >> 4, l16 = lane & 15;
    const int d = (blockIdx.x * blockDim.x + threadIdx.x) >> 6;
    if (d >= n) return;

    const float4 xrv = reinterpret_cast<const float4*>(xr + (size_t)d * 64)[l16];
    const float4 atv = reinterpret_cast<const float4*>(att)[l16];
    const int rp0 = row_ptr[d], rp1 = row_ptr[d + 1];

    float s = 0.f;
    float4 acc = {0.f, 0.f, 0.f, 0.f};
    int i = rp0 + g;
    for (; i + 4 < rp1; i += 8) {
        const int s0 = csr_src[i];
        const int s1 = csr_src[i + 4];
        const float4 a0 = bf4_to_f4(reinterpret_cast<const ushort4*>(xl + (size_t)s0 * 64)[l16]);
        const float4 a1 = bf4_to_f4(reinterpret_cast<const ushort4*>(xl + (size_t)s1 * 64)[l16]);
        float v, p0 = 0.f, p1 = 0.f;
        v = a0.x + xrv.x; p0 = fmaf(atv.x, (v > 0.f ? v : 0.2f * v), p0);
        v = a0.y + xrv.y; p0 = fmaf(atv.y, (v > 0.f ? v : 0.2f * v), p0);
        v = a0.z + xrv.z; p0 = fmaf(atv.z, (v > 0.f ? v : 0.2f * v), p0);
        v = a0.w + xrv.w; p0 = fmaf(atv.w, (v > 0.f ? v : 0.2f * v), p0);
        v = a1.x + xrv.x; p1 = fmaf(atv.x, (v > 0.f ? v : 0.2f * v), p1);
        v = a1.y + xrv.y; p1 = fmaf(atv.y, (v > 0.f ? v : 0.2f * v), p1);
        v = a1.z + xrv.z; p1 = fmaf(atv.z, (v > 0.f ? v : 0.2f * v), p1);
        v = a1.w + xrv.w; p1 = fmaf(atv.w, (v > 0.f ? v : 0.2f * v), p1);
#pragma unroll
        for (int msk = 8; msk >= 1; msk >>= 1) {
            p0 += __shfl_xor(p0, msk, 64);
            p1 += __shfl_xor(p1, msk, 64);
        }
        const float w0 = __expf(p0), w1 = __expf(p1);
        s += w0 + w1;
        acc.x = fmaf(w0, a0.x, fmaf(w1, a1.x, acc.x));
        acc.y = fmaf(w0, a0.y, fmaf(w1, a1.y, acc.y));
        acc.z = fmaf(w0, a0.z, fmaf(w1, a1.z, acc.z));
        acc.w = fmaf(w0, a0.w, fmaf(w1, a1.w, acc.w));
    }
    if (i < rp1) {
        const int s0 = csr_src[i];
        const float4 a0 = bf4_to_f4(reinterpret_cast<const ushort4*>(xl + (size_t)s0 * 64)[l16]);
        float v, p0 = 0.f;
        v = a0.x + xrv.x; p0 = fmaf(atv.x, (v > 0.f ? v : 0.2f * v), p0);
        v = a0.y + xrv.y; p0 = fmaf(atv.y, (v > 0.f ? v : 0.2f * v), p0);
        v = a0.z + xrv.z; p0 = fmaf(atv.z, (v > 0.f ? v : 0.2f * v), p0);
        v = a0.w + xrv.w; p0 = fmaf(atv.w, (v > 0.f ? v : 0.2f * v), p0);
#pragma unroll
        for (int msk = 8; msk >= 1; msk >>= 1) p0 += __shfl_xor(p0, msk, 64);
        const float w0 = __expf(p0);
        s += w0;
        acc.x = fmaf(w0, a0.x, acc.x);
        acc.y = fmaf(w0, a0.y, acc.y);
        acc.z = fmaf(w0, a0.z, acc.z);
        acc.w = fmaf(w0, a0.w, acc.w);
    }
#pragma unroll
    for (int off = 16; off <= 32; off <<= 1) {
        s += __shfl_xor(s, off, 64);
        acc.x += __shfl_xor(acc.x, off, 64);
        acc.y += __shfl_xor(acc.y, off, 64);
        acc.z += __shfl_xor(acc.z, off, 64);
        acc.w += __shfl_xor(acc.w, off, 64);
    }
    if (g == 0) {
        const float inv = 1.f / (s + 1e-16f);
        const float4 bv = reinterpret_cast<const float4*>(bias)[l16];
        float4 o;
        o.x = fmaxf(fmaf(acc.x, inv, bv.x), 0.f);
        o.y = fmaxf(fmaf(acc.y, inv, bv.y), 0.f);
        o.z = fmaxf(fmaf(acc.z, inv, bv.z), 0.f);
        o.w = fmaxf(fmaf(acc.w, inv, bv.w), 0.f);
        reinterpret_cast<float4*>(out + (size_t)d * 64)[l16] = o;
    }
}

extern "C" void kernel_launch(void* const* d_in, const int* in_sizes, int n_in,
                              void* d_out, int out_size, void* d_ws, size_t ws_size,
                              hipStream_t stream) {
    const float* x    = (const float*)d_in[0];
    const int*   ei   = (const int*)d_in[1];
    const float* Wl1  = (const float*)d_in[2];
    const float* Wr1  = (const float*)d_in[3];
    const float* att1 = (const float*)d_in[4];
    const float* b1   = (const float*)d_in[5];
    const float* Wl2  = (const float*)d_in[6];
    const float* Wr2  = (const float*)d_in[7];
    const float* att2 = (const float*)d_in[8];
    const float* b2   = (const float*)d_in[9];

    const int n    = in_sizes[0] / 128;   // 50000
    const int e0   = in_sizes[1] / 2;     // 800000
    const int etot = e0 + n;
    const int* srcs = ei;
    const int* dsts = ei + e0;

    float* ws = (float*)d_ws;
    ush*   xhi  = (ush*)ws;                        // n*128 ush (reused h1hi)
    ush*   xlo  = (ush*)(ws + (size_t)n * 64);     // n*128 ush (reused h1lo)
    ush*   xlbf = (ush*)(ws + (size_t)n * 128);    // n*128 ush
    float* xr   = ws + (size_t)n * 192;            // n*128 f32
    int* row_ptr = (int*)(ws + (size_t)n * 320);   // n+2 (pad for alignment)
    int* ghist   = row_ptr + (n + 2);              // 512
    int* boff    = ghist + 512;                    // 512
    int* cur     = boff + 512;                     // 512
    int* csr_src = cur + 512;                      // etot
    int2* pairs  = (int2*)(csr_src + etot);        // etot int2 (8B aligned)
    ush* wph     = (ush*)(pairs + etot);           // 96*512 ush
    ush* wpl     = wph + 96 * 512;                 // 96*512 ush

    const int NB = (n + 127) / 128;                // 391 <= 512
    const int nblka = (etot + 2047) / 2048;

    // ---- CSR build via 2-level counting sort ----
    hipMemsetAsync(ghist, 0, 512 * sizeof(int), stream);
    hist_k<<<256, 256, 0, stream>>>(dsts, ghist, e0, etot);
    scanb_k<<<1, 512, 0, stream>>>(ghist, boff, cur);
    semisort_k<<<nblka, 256, 0, stream>>>(srcs, dsts, cur, pairs, e0, etot);
    bucket_fill_k<<<NB, 256, 0, stream>>>(pairs, boff, row_ptr, csr_src, n, etot);

    // ---- precision-split preps ----
    prep_w_k<<<96, 64, 0, stream>>>(Wl1, Wr1, Wl2, Wr2, wph, wpl);
    prep_x_k<<<2048, 256, 0, stream>>>(x, xhi, xlo, n * 32);

    const int gx = (n + 63) / 64;

    // ---- layer 1 (H=2): xl bf16 [n,128], xr f32 [n,128] ----
    gemm_mfma_k<128><<<dim3(gx, 4), 256, 0, stream>>>(
        xhi, xlo, wph, wpl, wph + 32 * 512, wpl + 32 * 512, xlbf, xr, n);
    gat_dst2_k<<<(n + 3) / 4, 256, 0, stream>>>(xlbf, xr, row_ptr, csr_src,
                                                att1, b1, xhi, xlo, n);

    // ---- layer 2 (H=1): xl2 bf16 [n,64], xr2 f32 [n,64] ----
    gemm_mfma_k<64><<<dim3(gx, 2), 256, 0, stream>>>(
        xhi, xlo, wph + 64 * 512, wpl + 64 * 512, wph + 80 * 512, wpl + 80 * 512,
        xlbf, xr, n);
    gat_dst1_k<<<(n + 3) / 4, 256, 0, stream>>>(xlbf, xr, row_ptr, csr_src,
                                                att2, b2, (float*)d_out, n);
}